// Round 1
// baseline (2346.681 us; speedup 1.0000x reference)
//
#include <hip/hip_runtime.h>
#include <math.h>

#define HID 128

__device__ __forceinline__ float gelu_f(float x){
  return 0.5f*x*(1.0f+erff(x*0.70710678118654752440f));
}
__device__ __forceinline__ unsigned enc_ord(float f){
  unsigned b=__float_as_uint(f);
  return b ^ ((b>>31) ? 0xFFFFFFFFu : 0x80000000u);
}
__device__ __forceinline__ float dec_ord(unsigned u){
  unsigned b = (u & 0x80000000u) ? (u ^ 0x80000000u) : ~u;
  return __uint_as_float(b);
}

// o[row, j] = sum_k x[row,k]*W[k,j] + b[j]   (x is nrows x 128, W is 128 x OUT)
template<int OUT, int RPB>
__global__ void rowmm(const float* __restrict__ x, const float* __restrict__ W,
                      const float* __restrict__ b, float* __restrict__ o, int nrows) {
  int t = threadIdx.x;            // 128 threads
  int r0 = blockIdx.x * RPB;
  __shared__ float xs[RPB][128];
  for (int r = 0; r < RPB; r++) {
    int row = r0 + r;
    xs[r][t] = (row < nrows) ? x[(size_t)row*128 + t] : 0.f;
  }
  __syncthreads();
  const int NJ = OUT/128;
  float acc[RPB][NJ] = {};
  for (int k = 0; k < 128; k++) {
    float wv[NJ];
#pragma unroll
    for (int jj = 0; jj < NJ; jj++) wv[jj] = W[(size_t)k*OUT + t + jj*128];
#pragma unroll
    for (int r = 0; r < RPB; r++) {
      float xv = xs[r][k];
#pragma unroll
      for (int jj = 0; jj < NJ; jj++) acc[r][jj] += xv * wv[jj];
    }
  }
  for (int r = 0; r < RPB; r++) {
    int row = r0 + r;
    if (row >= nrows) break;
#pragma unroll
    for (int jj = 0; jj < NJ; jj++)
      o[(size_t)row*OUT + t + jj*128] = acc[r][jj] + b[t + jj*128];
  }
}

// kt[n,h,e] = sum_d k[n,h,d]*arel[h,d,e]; vt likewise with mrel.
// o layout: rows of 384, k at +0, v at +256
__global__ void rel_transform(const float* __restrict__ o,
                              const float* __restrict__ arel, const float* __restrict__ mrel,
                              float* __restrict__ kt, float* __restrict__ vt,
                              int n, int rpb) {
  int t = threadIdx.x;            // 128
  int h = t >> 5, e = t & 31;
  float ar[32], mr[32];
#pragma unroll
  for (int d = 0; d < 32; d++) {
    ar[d] = arel[(h*32 + d)*32 + e];
    mr[d] = mrel[(h*32 + d)*32 + e];
  }
  __shared__ float ks[128], vs[128];
  int rbeg = blockIdx.x * rpb;
  int rend = rbeg + rpb; if (rend > n) rend = n;
  for (int row = rbeg; row < rend; row++) {
    __syncthreads();
    ks[t] = o[(size_t)row*384 + t];
    vs[t] = o[(size_t)row*384 + 256 + t];
    __syncthreads();
    float ak = 0.f, av = 0.f;
#pragma unroll
    for (int d = 0; d < 32; d++) {
      ak += ks[h*32 + d] * ar[d];
      av += vs[h*32 + d] * mr[d];
    }
    kt[(size_t)row*128 + t] = ak;
    vt[(size_t)row*128 + t] = av;
  }
}

// pass A: alpha[e,h] = dot(q[dst,h,:], kt[src,h,:]) * prel[h] * inv_sqrt_d ; atomic max into m
__global__ void edge_score(const float* __restrict__ oq, const float* __restrict__ kt,
                           const int* __restrict__ ei, int E,
                           const float* __restrict__ prel,
                           float* __restrict__ alpha, unsigned* __restrict__ m, int off) {
  int i = blockIdx.x*blockDim.x + threadIdx.x;
  if (i >= E*4) return;
  int e = i >> 2, h = i & 3;
  int src = ei[e], dst = ei[E + e];
  const float* qp = oq + (size_t)dst*384 + 128 + h*32;
  const float* kp = kt + (size_t)src*128 + h*32;
  float a = 0.f;
#pragma unroll
  for (int d = 0; d < 32; d++) a += qp[d]*kp[d];
  a = a * prel[h];
  a = a * 0.17677669529663688f;   // 1/sqrt(32) as fp32
  alpha[i] = a;
  atomicMax(m + (size_t)(dst + off)*4 + h, enc_ord(a));
}

// pass B: alpha <- exp(alpha - m[dst]); atomicAdd into s
__global__ void edge_exp(const int* __restrict__ ei, int E,
                         float* __restrict__ alpha, const unsigned* __restrict__ m,
                         float* __restrict__ s, int off) {
  int i = blockIdx.x*blockDim.x + threadIdx.x;
  if (i >= E*4) return;
  int e = i >> 2, h = i & 3;
  int dst = ei[E + e] + off;
  float mf = dec_ord(m[(size_t)dst*4 + h]);
  float ex = expf(alpha[i] - mf);
  alpha[i] = ex;
  atomicAdd(s + (size_t)dst*4 + h, ex);
}

// pass C: agg[dst, :] += (alpha/s) * vt[src, :]   (128 threads per edge, 2 edges/block)
__global__ void edge_agg(const int* __restrict__ ei, int E,
                         const float* __restrict__ alpha, const float* __restrict__ s,
                         const float* __restrict__ vt, float* __restrict__ agg, int off) {
  int e = blockIdx.x*2 + (threadIdx.x >> 7);
  if (e >= E) return;
  int t = threadIdx.x & 127;
  int h = t >> 5;
  int src = ei[e], dst = ei[E + e] + off;
  float w = alpha[(size_t)e*4 + h] / (s[(size_t)dst*4 + h] + 1e-16f);
  atomicAdd(agg + (size_t)dst*128 + t, w * vt[(size_t)src*128 + t]);
}

// finish: g = gelu(agg_row) @ Wout + bout; v = sig(skip)*g + (1-sig)*x; optionally gelu; in-place on h
template<int RPB>
__global__ void finishk(float* __restrict__ hbuf, const float* __restrict__ agg, int agg_off,
                        const float* __restrict__ Wo, const float* __restrict__ bo,
                        const float* __restrict__ skipp, int do_gelu, int nrows) {
  int t = threadIdx.x;            // 128
  int r0 = blockIdx.x * RPB;
  __shared__ float gs[RPB][128];
  for (int r = 0; r < RPB; r++) {
    int row = r0 + r;
    float a = (row < nrows) ? agg[(size_t)(row + agg_off)*128 + t] : 0.f;
    gs[r][t] = gelu_f(a);
  }
  __syncthreads();
  float acc[RPB] = {};
  for (int k = 0; k < 128; k++) {
    float wv = Wo[(size_t)k*128 + t];
#pragma unroll
    for (int r = 0; r < RPB; r++) acc[r] += gs[r][k]*wv;
  }
  float sg = 1.f/(1.f + expf(-skipp[0]));
  for (int r = 0; r < RPB; r++) {
    int row = r0 + r;
    if (row >= nrows) break;
    float g = acc[r] + bo[t];
    float v = sg*g + (1.f - sg)*hbuf[(size_t)row*128 + t];
    hbuf[(size_t)row*128 + t] = do_gelu ? gelu_f(v) : v;
  }
}

// LayerNorm over 128 then gelu, in place. One wave (64 lanes) per row, 4 rows / 256-block.
__global__ void ln_gelu(float* __restrict__ h, const float* __restrict__ g,
                        const float* __restrict__ b, int nrows) {
  int idx = blockIdx.x*blockDim.x + threadIdx.x;
  int row = idx >> 6, lane = idx & 63;
  if (row >= nrows) return;
  float x0 = h[(size_t)row*128 + lane];
  float x1 = h[(size_t)row*128 + 64 + lane];
  float sum = x0 + x1;
#pragma unroll
  for (int o = 32; o; o >>= 1) sum += __shfl_xor(sum, o, 64);
  float mu = sum * (1.f/128.f);
  float d0 = x0 - mu, d1 = x1 - mu;
  float vs = d0*d0 + d1*d1;
#pragma unroll
  for (int o = 32; o; o >>= 1) vs += __shfl_xor(vs, o, 64);
  float inv = 1.f / sqrtf(vs*(1.f/128.f) + 1e-5f);
  h[(size_t)row*128 + lane]      = gelu_f(d0*inv*g[lane] + b[lane]);
  h[(size_t)row*128 + 64 + lane] = gelu_f(d1*inv*g[64 + lane] + b[64 + lane]);
}

// x1[n] = dot(h[n,:], Wgat[:,0]) — one wave per row
__global__ void gat_x1(const float* __restrict__ h, const float* __restrict__ Wg,
                       float* __restrict__ x1, int N) {
  int idx = blockIdx.x*blockDim.x + threadIdx.x;
  int row = idx >> 6, lane = idx & 63;
  if (row >= N) return;
  float a = h[(size_t)row*128 + lane]*Wg[lane] + h[(size_t)row*128 + 64 + lane]*Wg[64 + lane];
#pragma unroll
  for (int o = 32; o; o >>= 1) a += __shfl_xor(a, o, 64);
  if (lane == 0) x1[row] = a;
}

__device__ __forceinline__ void gat_edge_idx(int i, const int* aa, const int* ab, const int* ba,
                                             int Eaa, int Eab, int Eba, int Na,
                                             int& src, int& dst) {
  if (i < Eaa)              { src = aa[i];                 dst = aa[Eaa + i]; }
  else if (i < Eaa+Eab)     { int j=i-Eaa;      src = ab[j];      dst = ab[Eab + j] + Na; }
  else if (i < Eaa+Eab+Eba) { int j=i-Eaa-Eab;  src = ba[j] + Na; dst = ba[Eba + j]; }
  else                      { int j=i-Eaa-Eab-Eba; src = j; dst = j; }
}

__global__ void gatA(const float* __restrict__ x1, const int* aa, const int* ab, const int* ba,
                     int Eaa, int Eab, int Eba, int Na, int total,
                     const float* __restrict__ asrc, const float* __restrict__ adst,
                     float* __restrict__ esc, unsigned* __restrict__ m1) {
  int i = blockIdx.x*blockDim.x + threadIdx.x;
  if (i >= total) return;
  int src, dst;
  gat_edge_idx(i, aa, ab, ba, Eaa, Eab, Eba, Na, src, dst);
  float e = x1[src]*asrc[0] + x1[dst]*adst[0];
  e = (e > 0.f) ? e : 0.2f*e;
  esc[i] = e;
  atomicMax(m1 + dst, enc_ord(e));
}

__global__ void gatB(const int* aa, const int* ab, const int* ba,
                     int Eaa, int Eab, int Eba, int Na, int total,
                     float* __restrict__ esc, const unsigned* __restrict__ m1,
                     float* __restrict__ s1) {
  int i = blockIdx.x*blockDim.x + threadIdx.x;
  if (i >= total) return;
  int src, dst;
  gat_edge_idx(i, aa, ab, ba, Eaa, Eab, Eba, Na, src, dst);
  float ex = expf(esc[i] - dec_ord(m1[dst]));
  esc[i] = ex;
  atomicAdd(s1 + dst, ex);
}

__global__ void gatC(const int* aa, const int* ab, const int* ba,
                     int Eaa, int Eab, int Eba, int Na, int total,
                     const float* __restrict__ esc, const float* __restrict__ s1,
                     const float* __restrict__ x1, float* __restrict__ score) {
  int i = blockIdx.x*blockDim.x + threadIdx.x;
  if (i >= total) return;
  int src, dst;
  gat_edge_idx(i, aa, ab, ba, Eaa, Eab, Eba, Na, src, dst);
  float w = esc[i] / (s1[dst] + 1e-16f);
  atomicAdd(score + dst, w * x1[src]);
}

// exact top-8 with index tie-break (smaller index wins); vals sorted descending
__global__ void topk8(const float* __restrict__ score, const float* __restrict__ bgat,
                      int N, float* __restrict__ vals, int* __restrict__ perm) {
  __shared__ float bv[256];
  __shared__ int   bi[256];
  __shared__ int   seli[8];
  int t = threadIdx.x;
  float bg = bgat[0];
  for (int k = 0; k < 8; k++) {
    float best = -INFINITY; int besti = N;
    for (int i = t; i < N; i += 256) {
      bool taken = false;
      for (int j = 0; j < k; j++) if (seli[j] == i) taken = true;
      if (taken) continue;
      float v = score[i] + bg;
      if (v > best || (v == best && i < besti)) { best = v; besti = i; }
    }
    bv[t] = best; bi[t] = besti;
    __syncthreads();
    for (int o = 128; o; o >>= 1) {
      if (t < o) {
        if (bv[t+o] > bv[t] || (bv[t+o] == bv[t] && bi[t+o] < bi[t])) { bv[t]=bv[t+o]; bi[t]=bi[t+o]; }
      }
      __syncthreads();
    }
    if (t == 0) { seli[k] = bi[0]; vals[k] = bv[0]; perm[k] = bi[0]; }
    __syncthreads();
  }
}

__global__ void mlp_final(const float* __restrict__ h, const float* __restrict__ vals,
                          const int* __restrict__ perm,
                          const float* __restrict__ W1, const float* __restrict__ b1,
                          const float* __restrict__ W2, const float* __restrict__ b2,
                          const float* __restrict__ W3, const float* __restrict__ b3,
                          float* __restrict__ out) {
  __shared__ float hp[1024], v1[128], v2[64];
  int t = threadIdx.x;  // 256
  for (int i = t; i < 1024; i += 256) {
    int r = i >> 7, d = i & 127;
    hp[i] = h[(size_t)perm[r]*128 + d] * tanhf(vals[r]);
  }
  __syncthreads();
  if (t < 128) {
    float a = 0.f;
    for (int k = 0; k < 1024; k++) a += hp[k]*W1[(size_t)k*128 + t];
    v1[t] = gelu_f(a + b1[t]);
  }
  __syncthreads();
  if (t < 64) {
    float a = 0.f;
    for (int k = 0; k < 128; k++) a += v1[k]*W2[(size_t)k*64 + t];
    v2[t] = gelu_f(a + b2[t]);
  }
  __syncthreads();
  if (t < 16) {
    float a = 0.f;
    for (int k = 0; k < 64; k++) a += v2[k]*W3[(size_t)k*16 + t];
    float r = gelu_f(a + b3[t]);
    if (isnan(r)) r = 0.f;
    else if (isinf(r)) r = (r > 0.f) ? 3.4028234663852886e38f : -3.4028234663852886e38f;
    out[t] = r;
  }
}

extern "C" void kernel_launch(void* const* d_in, const int* in_sizes, int n_in,
                              void* d_out, int out_size, void* d_ws, size_t ws_size,
                              hipStream_t stream) {
  const float* x_a  = (const float*)d_in[0];
  const float* x_b  = (const float*)d_in[1];
  const int* ei_aa  = (const int*)d_in[2];
  const int* ei_ab  = (const int*)d_in[3];
  const int* ei_ba  = (const int*)d_in[4];
  const float* Wkqv = (const float*)d_in[5];
  const float* bkqv = (const float*)d_in[6];
  const float* Wout = (const float*)d_in[7];
  const float* bout = (const float*)d_in[8];
  const float* skip = (const float*)d_in[9];
  const float* arel = (const float*)d_in[10];
  const float* mrel = (const float*)d_in[11];
  const float* prel = (const float*)d_in[12];
  const float* ln_g = (const float*)d_in[13];
  const float* ln_b = (const float*)d_in[14];
  const float* Wgat = (const float*)d_in[15];
  const float* att_src = (const float*)d_in[16];
  const float* att_dst = (const float*)d_in[17];
  const float* bgat = (const float*)d_in[18];
  const float* W1 = (const float*)d_in[19];
  const float* b1 = (const float*)d_in[20];
  const float* W2 = (const float*)d_in[21];
  const float* b2 = (const float*)d_in[22];
  const float* W3 = (const float*)d_in[23];
  const float* b3 = (const float*)d_in[24];

  int Na = in_sizes[0]/128, Nb = in_sizes[1]/128, N = Na + Nb;
  int Eaa = in_sizes[2]/2, Eab = in_sizes[3]/2, Eba = in_sizes[4]/2;

  // workspace layout
  float* w = (float*)d_ws;
  size_t off = 0;
  auto alloc = [&](size_t n) { float* p = w + off; off += n; return p; };
  float* hbuf = alloc((size_t)N*128);           // h_a = hbuf, h_b = hbuf + Na*128
  float* o_a  = alloc((size_t)Na*384);
  float* o_b  = alloc((size_t)Nb*384);
  float* kt0  = alloc((size_t)Na*128);
  float* kt1  = alloc((size_t)Na*128);
  float* kt2  = alloc((size_t)Nb*128);
  float* vt0  = alloc((size_t)Na*128);
  float* vt1  = alloc((size_t)Na*128);
  float* vt2  = alloc((size_t)Nb*128);
  float* alpha0 = alloc((size_t)Eaa*4);
  float* alpha1 = alloc((size_t)Eab*4);
  float* alpha2 = alloc((size_t)Eba*4);
  unsigned* mseg = (unsigned*)alloc((size_t)N*4);
  float* sseg  = alloc((size_t)N*4);
  float* agg   = alloc((size_t)N*128);
  float* x1buf = alloc((size_t)N);
  unsigned* m1 = (unsigned*)alloc((size_t)N);
  float* s1    = alloc((size_t)N);
  float* score = alloc((size_t)N);
  float* valsb = alloc(8);
  int*   permb = (int*)alloc(8);
  float* esc   = alpha0;  // reuse: 3E*4 floats >= 3E + N

  float* h_a = hbuf;
  float* h_b = hbuf + (size_t)Na*128;

  hipMemcpyAsync(h_a, x_a, (size_t)Na*128*sizeof(float), hipMemcpyDeviceToDevice, stream);
  hipMemcpyAsync(h_b, x_b, (size_t)Nb*128*sizeof(float), hipMemcpyDeviceToDevice, stream);

  const int RPB = 8;
  int rel_rpb_a = (Na + 1023)/1024, rel_rpb_b = (Nb + 1023)/1024;

  for (int L = 0; L < 3; L++) {
    // KQV per type
    rowmm<384,8><<<dim3((Na+RPB-1)/RPB),dim3(128),0,stream>>>(h_a, Wkqv + (size_t)(L*2+0)*128*384, bkqv + (L*2+0)*384, o_a, Na);
    rowmm<384,8><<<dim3((Nb+RPB-1)/RPB),dim3(128),0,stream>>>(h_b, Wkqv + (size_t)(L*2+1)*128*384, bkqv + (L*2+1)*384, o_b, Nb);
    // relation transforms (et0,et1 source type a; et2 source type b)
    rel_transform<<<dim3(1024),dim3(128),0,stream>>>(o_a, arel + (size_t)(L*3+0)*4096, mrel + (size_t)(L*3+0)*4096, kt0, vt0, Na, rel_rpb_a);
    rel_transform<<<dim3(1024),dim3(128),0,stream>>>(o_a, arel + (size_t)(L*3+1)*4096, mrel + (size_t)(L*3+1)*4096, kt1, vt1, Na, rel_rpb_a);
    rel_transform<<<dim3(1024),dim3(128),0,stream>>>(o_b, arel + (size_t)(L*3+2)*4096, mrel + (size_t)(L*3+2)*4096, kt2, vt2, Nb, rel_rpb_b);
    // zero segment buffers
    hipMemsetAsync(mseg, 0, (size_t)N*4*sizeof(unsigned), stream);
    hipMemsetAsync(sseg, 0, (size_t)N*4*sizeof(float), stream);
    hipMemsetAsync(agg, 0, (size_t)N*128*sizeof(float), stream);
    // pass A (scores + segment max).  et0: q=a, off 0; et1: q=b, off Na; et2: q=a, off 0
    edge_score<<<dim3((Eaa*4+255)/256),dim3(256),0,stream>>>(o_a, kt0, ei_aa, Eaa, prel + (L*3+0)*4, alpha0, mseg, 0);
    edge_score<<<dim3((Eab*4+255)/256),dim3(256),0,stream>>>(o_b, kt1, ei_ab, Eab, prel + (L*3+1)*4, alpha1, mseg, Na);
    edge_score<<<dim3((Eba*4+255)/256),dim3(256),0,stream>>>(o_a, kt2, ei_ba, Eba, prel + (L*3+2)*4, alpha2, mseg, 0);
    // pass B (exp + segment sum)
    edge_exp<<<dim3((Eaa*4+255)/256),dim3(256),0,stream>>>(ei_aa, Eaa, alpha0, mseg, sseg, 0);
    edge_exp<<<dim3((Eab*4+255)/256),dim3(256),0,stream>>>(ei_ab, Eab, alpha1, mseg, sseg, Na);
    edge_exp<<<dim3((Eba*4+255)/256),dim3(256),0,stream>>>(ei_ba, Eba, alpha2, mseg, sseg, 0);
    // pass C (weighted message scatter)
    edge_agg<<<dim3((Eaa+1)/2),dim3(256),0,stream>>>(ei_aa, Eaa, alpha0, sseg, vt0, agg, 0);
    edge_agg<<<dim3((Eab+1)/2),dim3(256),0,stream>>>(ei_ab, Eab, alpha1, sseg, vt1, agg, Na);
    edge_agg<<<dim3((Eba+1)/2),dim3(256),0,stream>>>(ei_ba, Eba, alpha2, sseg, vt2, agg, 0);
    // finish (gelu -> Wout -> gated skip; gelu inside except L0 where LN comes first)
    int do_gelu = (L == 0) ? 0 : 1;
    finishk<8><<<dim3((Na+7)/8),dim3(128),0,stream>>>(h_a, agg, 0,  Wout + (size_t)(L*2+0)*16384, bout + (L*2+0)*128, skip + L*2+0, do_gelu, Na);
    finishk<8><<<dim3((Nb+7)/8),dim3(128),0,stream>>>(h_b, agg, Na, Wout + (size_t)(L*2+1)*16384, bout + (L*2+1)*128, skip + L*2+1, do_gelu, Nb);
    if (L == 0) {
      ln_gelu<<<dim3((Na+3)/4),dim3(256),0,stream>>>(h_a, ln_g,       ln_b,       Na);
      ln_gelu<<<dim3((Nb+3)/4),dim3(256),0,stream>>>(h_b, ln_g + 128, ln_b + 128, Nb);
    }
  }

  // ---- GAT scorer + SAGPool top-k + MLP ----
  int total = Eaa + Eab + Eba + N;
  gat_x1<<<dim3((N+3)/4),dim3(256),0,stream>>>(hbuf, Wgat, x1buf, N);
  hipMemsetAsync(m1, 0, (size_t)N*sizeof(unsigned), stream);
  hipMemsetAsync(s1, 0, (size_t)N*sizeof(float), stream);
  hipMemsetAsync(score, 0, (size_t)N*sizeof(float), stream);
  gatA<<<dim3((total+255)/256),dim3(256),0,stream>>>(x1buf, ei_aa, ei_ab, ei_ba, Eaa, Eab, Eba, Na, total, att_src, att_dst, esc, m1);
  gatB<<<dim3((total+255)/256),dim3(256),0,stream>>>(ei_aa, ei_ab, ei_ba, Eaa, Eab, Eba, Na, total, esc, m1, s1);
  gatC<<<dim3((total+255)/256),dim3(256),0,stream>>>(ei_aa, ei_ab, ei_ba, Eaa, Eab, Eba, Na, total, esc, s1, x1buf, score);
  topk8<<<dim3(1),dim3(256),0,stream>>>(score, bgat, N, valsb, permb);
  mlp_final<<<dim3(1),dim3(256),0,stream>>>(hbuf, valsb, permb, W1, b1, W2, b2, W3, b3, (float*)d_out);
}

// Round 2
// 1878.801 us; speedup vs baseline: 1.2490x; 1.2490x over previous
//
#include <hip/hip_runtime.h>
#include <math.h>

#define HID 128

__device__ __forceinline__ float gelu_f(float x){
  return 0.5f*x*(1.0f+erff(x*0.70710678118654752440f));
}
__device__ __forceinline__ unsigned enc_ord(float f){
  unsigned b=__float_as_uint(f);
  return b ^ ((b>>31) ? 0xFFFFFFFFu : 0x80000000u);
}
__device__ __forceinline__ float dec_ord(unsigned u){
  unsigned b = (u & 0x80000000u) ? (u ^ 0x80000000u) : ~u;
  return __uint_as_float(b);
}

// o[row, j] = sum_k x[row,k]*W[k,j] + b[j]   (x is nrows x 128, W is 128 x OUT)
template<int OUT, int RPB>
__global__ void rowmm(const float* __restrict__ x, const float* __restrict__ W,
                      const float* __restrict__ b, float* __restrict__ o, int nrows) {
  int t = threadIdx.x;            // 128 threads
  int r0 = blockIdx.x * RPB;
  __shared__ float xs[RPB][128];
  for (int r = 0; r < RPB; r++) {
    int row = r0 + r;
    xs[r][t] = (row < nrows) ? x[(size_t)row*128 + t] : 0.f;
  }
  __syncthreads();
  const int NJ = OUT/128;
  float acc[RPB][NJ] = {};
  for (int k = 0; k < 128; k++) {
    float wv[NJ];
#pragma unroll
    for (int jj = 0; jj < NJ; jj++) wv[jj] = W[(size_t)k*OUT + t + jj*128];
#pragma unroll
    for (int r = 0; r < RPB; r++) {
      float xv = xs[r][k];
#pragma unroll
      for (int jj = 0; jj < NJ; jj++) acc[r][jj] += xv * wv[jj];
    }
  }
  for (int r = 0; r < RPB; r++) {
    int row = r0 + r;
    if (row >= nrows) break;
#pragma unroll
    for (int jj = 0; jj < NJ; jj++)
      o[(size_t)row*OUT + t + jj*128] = acc[r][jj] + b[t + jj*128];
  }
}

// kt[n,h,e] = sum_d k[n,h,d]*arel[h,d,e]; vt likewise with mrel.
// o layout: rows of 384, k at +0, v at +256
__global__ void rel_transform(const float* __restrict__ o,
                              const float* __restrict__ arel, const float* __restrict__ mrel,
                              float* __restrict__ kt, float* __restrict__ vt,
                              int n, int rpb) {
  int t = threadIdx.x;            // 128
  int h = t >> 5, e = t & 31;
  float ar[32], mr[32];
#pragma unroll
  for (int d = 0; d < 32; d++) {
    ar[d] = arel[(h*32 + d)*32 + e];
    mr[d] = mrel[(h*32 + d)*32 + e];
  }
  __shared__ float ks[128], vs[128];
  int rbeg = blockIdx.x * rpb;
  int rend = rbeg + rpb; if (rend > n) rend = n;
  for (int row = rbeg; row < rend; row++) {
    __syncthreads();
    ks[t] = o[(size_t)row*384 + t];
    vs[t] = o[(size_t)row*384 + 256 + t];
    __syncthreads();
    float ak = 0.f, av = 0.f;
#pragma unroll
    for (int d = 0; d < 32; d++) {
      ak += ks[h*32 + d] * ar[d];
      av += vs[h*32 + d] * mr[d];
    }
    kt[(size_t)row*128 + t] = ak;
    vt[(size_t)row*128 + t] = av;
  }
}

// pass A: alpha[e,h] = dot(q[dst,h,:], kt[src,h,:]) * prel[h] * inv_sqrt_d ; atomic max into m
__global__ void edge_score(const float* __restrict__ oq, const float* __restrict__ kt,
                           const int* __restrict__ ei, int E,
                           const float* __restrict__ prel,
                           float* __restrict__ alpha, unsigned* __restrict__ m, int off) {
  int i = blockIdx.x*blockDim.x + threadIdx.x;
  if (i >= E*4) return;
  int e = i >> 2, h = i & 3;
  int src = ei[e], dst = ei[E + e];
  const float* qp = oq + (size_t)dst*384 + 128 + h*32;
  const float* kp = kt + (size_t)src*128 + h*32;
  float a = 0.f;
#pragma unroll
  for (int d = 0; d < 32; d++) a += qp[d]*kp[d];
  a = a * prel[h];
  a = a * 0.17677669529663688f;   // 1/sqrt(32) as fp32
  alpha[i] = a;
  atomicMax(m + (size_t)(dst + off)*4 + h, enc_ord(a));
}

// pass B: alpha <- exp(alpha - m[dst]); atomicAdd into s
__global__ void edge_exp(const int* __restrict__ ei, int E,
                         float* __restrict__ alpha, const unsigned* __restrict__ m,
                         float* __restrict__ s, int off) {
  int i = blockIdx.x*blockDim.x + threadIdx.x;
  if (i >= E*4) return;
  int e = i >> 2, h = i & 3;
  int dst = ei[E + e] + off;
  float mf = dec_ord(m[(size_t)dst*4 + h]);
  float ex = expf(alpha[i] - mf);
  alpha[i] = ex;
  atomicAdd(s + (size_t)dst*4 + h, ex);
}

// pass C: agg[dst, :] += (alpha/s) * vt[src, :]   (128 threads per edge, 2 edges/block)
__global__ void edge_agg(const int* __restrict__ ei, int E,
                         const float* __restrict__ alpha, const float* __restrict__ s,
                         const float* __restrict__ vt, float* __restrict__ agg, int off) {
  int e = blockIdx.x*2 + (threadIdx.x >> 7);
  if (e >= E) return;
  int t = threadIdx.x & 127;
  int h = t >> 5;
  int src = ei[e], dst = ei[E + e] + off;
  float w = alpha[(size_t)e*4 + h] / (s[(size_t)dst*4 + h] + 1e-16f);
  atomicAdd(agg + (size_t)dst*128 + t, w * vt[(size_t)src*128 + t]);
}

// finish: g = gelu(agg_row) @ Wout + bout; v = sig(skip)*g + (1-sig)*x; optionally gelu; in-place on h
template<int RPB>
__global__ void finishk(float* __restrict__ hbuf, const float* __restrict__ agg, int agg_off,
                        const float* __restrict__ Wo, const float* __restrict__ bo,
                        const float* __restrict__ skipp, int do_gelu, int nrows) {
  int t = threadIdx.x;            // 128
  int r0 = blockIdx.x * RPB;
  __shared__ float gs[RPB][128];
  for (int r = 0; r < RPB; r++) {
    int row = r0 + r;
    float a = (row < nrows) ? agg[(size_t)(row + agg_off)*128 + t] : 0.f;
    gs[r][t] = gelu_f(a);
  }
  __syncthreads();
  float acc[RPB] = {};
  for (int k = 0; k < 128; k++) {
    float wv = Wo[(size_t)k*128 + t];
#pragma unroll
    for (int r = 0; r < RPB; r++) acc[r] += gs[r][k]*wv;
  }
  float sg = 1.f/(1.f + expf(-skipp[0]));
  for (int r = 0; r < RPB; r++) {
    int row = r0 + r;
    if (row >= nrows) break;
    float g = acc[r] + bo[t];
    float v = sg*g + (1.f - sg)*hbuf[(size_t)row*128 + t];
    hbuf[(size_t)row*128 + t] = do_gelu ? gelu_f(v) : v;
  }
}

// LayerNorm over 128 then gelu, in place. One wave (64 lanes) per row, 4 rows / 256-block.
__global__ void ln_gelu(float* __restrict__ h, const float* __restrict__ g,
                        const float* __restrict__ b, int nrows) {
  int idx = blockIdx.x*blockDim.x + threadIdx.x;
  int row = idx >> 6, lane = idx & 63;
  if (row >= nrows) return;
  float x0 = h[(size_t)row*128 + lane];
  float x1 = h[(size_t)row*128 + 64 + lane];
  float sum = x0 + x1;
#pragma unroll
  for (int o = 32; o; o >>= 1) sum += __shfl_xor(sum, o, 64);
  float mu = sum * (1.f/128.f);
  float d0 = x0 - mu, d1 = x1 - mu;
  float vs = d0*d0 + d1*d1;
#pragma unroll
  for (int o = 32; o; o >>= 1) vs += __shfl_xor(vs, o, 64);
  float inv = 1.f / sqrtf(vs*(1.f/128.f) + 1e-5f);
  h[(size_t)row*128 + lane]      = gelu_f(d0*inv*g[lane] + b[lane]);
  h[(size_t)row*128 + 64 + lane] = gelu_f(d1*inv*g[64 + lane] + b[64 + lane]);
}

// x1[n] = dot(h[n,:], Wgat[:,0]) — one wave per row
__global__ void gat_x1(const float* __restrict__ h, const float* __restrict__ Wg,
                       float* __restrict__ x1, int N) {
  int idx = blockIdx.x*blockDim.x + threadIdx.x;
  int row = idx >> 6, lane = idx & 63;
  if (row >= N) return;
  float a = h[(size_t)row*128 + lane]*Wg[lane] + h[(size_t)row*128 + 64 + lane]*Wg[64 + lane];
#pragma unroll
  for (int o = 32; o; o >>= 1) a += __shfl_xor(a, o, 64);
  if (lane == 0) x1[row] = a;
}

__device__ __forceinline__ void gat_edge_idx(int i, const int* aa, const int* ab, const int* ba,
                                             int Eaa, int Eab, int Eba, int Na,
                                             int& src, int& dst) {
  if (i < Eaa)              { src = aa[i];                 dst = aa[Eaa + i]; }
  else if (i < Eaa+Eab)     { int j=i-Eaa;      src = ab[j];      dst = ab[Eab + j] + Na; }
  else if (i < Eaa+Eab+Eba) { int j=i-Eaa-Eab;  src = ba[j] + Na; dst = ba[Eba + j]; }
  else                      { int j=i-Eaa-Eab-Eba; src = j; dst = j; }
}

__global__ void gatA(const float* __restrict__ x1, const int* aa, const int* ab, const int* ba,
                     int Eaa, int Eab, int Eba, int Na, int total,
                     const float* __restrict__ asrc, const float* __restrict__ adst,
                     float* __restrict__ esc, unsigned* __restrict__ m1) {
  int i = blockIdx.x*blockDim.x + threadIdx.x;
  if (i >= total) return;
  int src, dst;
  gat_edge_idx(i, aa, ab, ba, Eaa, Eab, Eba, Na, src, dst);
  float e = x1[src]*asrc[0] + x1[dst]*adst[0];
  e = (e > 0.f) ? e : 0.2f*e;
  esc[i] = e;
  atomicMax(m1 + dst, enc_ord(e));
}

__global__ void gatB(const int* aa, const int* ab, const int* ba,
                     int Eaa, int Eab, int Eba, int Na, int total,
                     float* __restrict__ esc, const unsigned* __restrict__ m1,
                     float* __restrict__ s1) {
  int i = blockIdx.x*blockDim.x + threadIdx.x;
  if (i >= total) return;
  int src, dst;
  gat_edge_idx(i, aa, ab, ba, Eaa, Eab, Eba, Na, src, dst);
  float ex = expf(esc[i] - dec_ord(m1[dst]));
  esc[i] = ex;
  atomicAdd(s1 + dst, ex);
}

__global__ void gatC(const int* aa, const int* ab, const int* ba,
                     int Eaa, int Eab, int Eba, int Na, int total,
                     const float* __restrict__ esc, const float* __restrict__ s1,
                     const float* __restrict__ x1, float* __restrict__ score) {
  int i = blockIdx.x*blockDim.x + threadIdx.x;
  if (i >= total) return;
  int src, dst;
  gat_edge_idx(i, aa, ab, ba, Eaa, Eab, Eba, Na, src, dst);
  float w = esc[i] / (s1[dst] + 1e-16f);
  atomicAdd(score + dst, w * x1[src]);
}

// ---- parallel top-8 ----
// stage 1: each block owns a contiguous chunk (<=256 elems, 1/thread); 8 rounds of
// block argmax (val desc, idx asc) with pop-winner masking -> 8 candidates/block.
__global__ void topk_stage1(const float* __restrict__ score, const float* __restrict__ bgat,
                            int N, float* __restrict__ cvals, int* __restrict__ cidx) {
  __shared__ float bv[256];
  __shared__ int   bi[256];
  int t = threadIdx.x;
  int chunk = (N + gridDim.x - 1) / gridDim.x;   // <= 256 by construction
  int i = blockIdx.x * chunk + t;
  float bg = bgat[0];
  bool valid = (t < chunk && i < N);
  float myv = valid ? score[i] + bg : -INFINITY;
  int   myi = valid ? i : 0x7FFFFFFF;
  for (int k = 0; k < 8; k++) {
    bv[t] = myv; bi[t] = myi;
    __syncthreads();
    for (int o = 128; o; o >>= 1) {
      if (t < o) {
        if (bv[t+o] > bv[t] || (bv[t+o] == bv[t] && bi[t+o] < bi[t])) { bv[t]=bv[t+o]; bi[t]=bi[t+o]; }
      }
      __syncthreads();
    }
    if (t == 0) { cvals[blockIdx.x*8 + k] = bv[0]; cidx[blockIdx.x*8 + k] = bi[0]; }
    if (myi == bi[0]) myv = -INFINITY;   // pop winner from this thread
    __syncthreads();
  }
}

// stage 2: one block merges C candidates (global indices unique across blocks).
__global__ void topk_stage2(const float* __restrict__ cvals, const int* __restrict__ cidx,
                            int C, float* __restrict__ vals, int* __restrict__ perm) {
  __shared__ float bv[256];
  __shared__ int   bi[256];
  __shared__ int   seli[8];
  int t = threadIdx.x;
  for (int k = 0; k < 8; k++) {
    float best = -INFINITY; int besti = 0x7FFFFFFF;
    for (int i = t; i < C; i += 256) {
      int id = cidx[i];
      bool taken = false;
      for (int j = 0; j < k; j++) if (seli[j] == id) taken = true;
      if (taken) continue;
      float v = cvals[i];
      if (v > best || (v == best && id < besti)) { best = v; besti = id; }
    }
    bv[t] = best; bi[t] = besti;
    __syncthreads();
    for (int o = 128; o; o >>= 1) {
      if (t < o) {
        if (bv[t+o] > bv[t] || (bv[t+o] == bv[t] && bi[t+o] < bi[t])) { bv[t]=bv[t+o]; bi[t]=bi[t+o]; }
      }
      __syncthreads();
    }
    if (t == 0) { seli[k] = bi[0]; vals[k] = bv[0]; perm[k] = bi[0]; }
    __syncthreads();
  }
}

__global__ void mlp_final(const float* __restrict__ h, const float* __restrict__ vals,
                          const int* __restrict__ perm,
                          const float* __restrict__ W1, const float* __restrict__ b1,
                          const float* __restrict__ W2, const float* __restrict__ b2,
                          const float* __restrict__ W3, const float* __restrict__ b3,
                          float* __restrict__ out) {
  __shared__ float hp[1024], v1[128], v2[64];
  int t = threadIdx.x;  // 256
  for (int i = t; i < 1024; i += 256) {
    int r = i >> 7, d = i & 127;
    hp[i] = h[(size_t)perm[r]*128 + d] * tanhf(vals[r]);
  }
  __syncthreads();
  if (t < 128) {
    float a = 0.f;
    for (int k = 0; k < 1024; k++) a += hp[k]*W1[(size_t)k*128 + t];
    v1[t] = gelu_f(a + b1[t]);
  }
  __syncthreads();
  if (t < 64) {
    float a = 0.f;
    for (int k = 0; k < 128; k++) a += v1[k]*W2[(size_t)k*64 + t];
    v2[t] = gelu_f(a + b2[t]);
  }
  __syncthreads();
  if (t < 16) {
    float a = 0.f;
    for (int k = 0; k < 64; k++) a += v2[k]*W3[(size_t)k*16 + t];
    float r = gelu_f(a + b3[t]);
    if (isnan(r)) r = 0.f;
    else if (isinf(r)) r = (r > 0.f) ? 3.4028234663852886e38f : -3.4028234663852886e38f;
    out[t] = r;
  }
}

extern "C" void kernel_launch(void* const* d_in, const int* in_sizes, int n_in,
                              void* d_out, int out_size, void* d_ws, size_t ws_size,
                              hipStream_t stream) {
  const float* x_a  = (const float*)d_in[0];
  const float* x_b  = (const float*)d_in[1];
  const int* ei_aa  = (const int*)d_in[2];
  const int* ei_ab  = (const int*)d_in[3];
  const int* ei_ba  = (const int*)d_in[4];
  const float* Wkqv = (const float*)d_in[5];
  const float* bkqv = (const float*)d_in[6];
  const float* Wout = (const float*)d_in[7];
  const float* bout = (const float*)d_in[8];
  const float* skip = (const float*)d_in[9];
  const float* arel = (const float*)d_in[10];
  const float* mrel = (const float*)d_in[11];
  const float* prel = (const float*)d_in[12];
  const float* ln_g = (const float*)d_in[13];
  const float* ln_b = (const float*)d_in[14];
  const float* Wgat = (const float*)d_in[15];
  const float* att_src = (const float*)d_in[16];
  const float* att_dst = (const float*)d_in[17];
  const float* bgat = (const float*)d_in[18];
  const float* W1 = (const float*)d_in[19];
  const float* b1 = (const float*)d_in[20];
  const float* W2 = (const float*)d_in[21];
  const float* b2 = (const float*)d_in[22];
  const float* W3 = (const float*)d_in[23];
  const float* b3 = (const float*)d_in[24];

  int Na = in_sizes[0]/128, Nb = in_sizes[1]/128, N = Na + Nb;
  int Eaa = in_sizes[2]/2, Eab = in_sizes[3]/2, Eba = in_sizes[4]/2;

  // workspace layout
  float* w = (float*)d_ws;
  size_t off = 0;
  auto alloc = [&](size_t n) { float* p = w + off; off += n; return p; };
  float* hbuf = alloc((size_t)N*128);           // h_a = hbuf, h_b = hbuf + Na*128
  float* o_a  = alloc((size_t)Na*384);
  float* o_b  = alloc((size_t)Nb*384);
  float* kt0  = alloc((size_t)Na*128);
  float* kt1  = alloc((size_t)Na*128);
  float* kt2  = alloc((size_t)Nb*128);
  float* vt0  = alloc((size_t)Na*128);
  float* vt1  = alloc((size_t)Na*128);
  float* vt2  = alloc((size_t)Nb*128);
  float* alpha0 = alloc((size_t)Eaa*4);
  float* alpha1 = alloc((size_t)Eab*4);
  float* alpha2 = alloc((size_t)Eba*4);
  unsigned* mseg = (unsigned*)alloc((size_t)N*4);
  float* sseg  = alloc((size_t)N*4);
  float* agg   = alloc((size_t)N*128);
  float* x1buf = alloc((size_t)N);
  unsigned* m1 = (unsigned*)alloc((size_t)N);
  float* s1    = alloc((size_t)N);
  float* score = alloc((size_t)N);
  float* valsb = alloc(8);
  int*   permb = (int*)alloc(8);
  float* cvals = alloc(2048);
  int*   cidx  = (int*)alloc(2048);
  float* esc   = alpha0;  // reuse: 3E*4 floats >= 3E + N

  float* h_a = hbuf;
  float* h_b = hbuf + (size_t)Na*128;

  hipMemcpyAsync(h_a, x_a, (size_t)Na*128*sizeof(float), hipMemcpyDeviceToDevice, stream);
  hipMemcpyAsync(h_b, x_b, (size_t)Nb*128*sizeof(float), hipMemcpyDeviceToDevice, stream);

  const int RPB = 8;
  int rel_rpb_a = (Na + 1023)/1024, rel_rpb_b = (Nb + 1023)/1024;

  for (int L = 0; L < 3; L++) {
    // KQV per type
    rowmm<384,8><<<dim3((Na+RPB-1)/RPB),dim3(128),0,stream>>>(h_a, Wkqv + (size_t)(L*2+0)*128*384, bkqv + (L*2+0)*384, o_a, Na);
    rowmm<384,8><<<dim3((Nb+RPB-1)/RPB),dim3(128),0,stream>>>(h_b, Wkqv + (size_t)(L*2+1)*128*384, bkqv + (L*2+1)*384, o_b, Nb);
    // relation transforms (et0,et1 source type a; et2 source type b)
    rel_transform<<<dim3(1024),dim3(128),0,stream>>>(o_a, arel + (size_t)(L*3+0)*4096, mrel + (size_t)(L*3+0)*4096, kt0, vt0, Na, rel_rpb_a);
    rel_transform<<<dim3(1024),dim3(128),0,stream>>>(o_a, arel + (size_t)(L*3+1)*4096, mrel + (size_t)(L*3+1)*4096, kt1, vt1, Na, rel_rpb_a);
    rel_transform<<<dim3(1024),dim3(128),0,stream>>>(o_b, arel + (size_t)(L*3+2)*4096, mrel + (size_t)(L*3+2)*4096, kt2, vt2, Nb, rel_rpb_b);
    // zero segment buffers
    hipMemsetAsync(mseg, 0, (size_t)N*4*sizeof(unsigned), stream);
    hipMemsetAsync(sseg, 0, (size_t)N*4*sizeof(float), stream);
    hipMemsetAsync(agg, 0, (size_t)N*128*sizeof(float), stream);
    // pass A (scores + segment max).  et0: q=a, off 0; et1: q=b, off Na; et2: q=a, off 0
    edge_score<<<dim3((Eaa*4+255)/256),dim3(256),0,stream>>>(o_a, kt0, ei_aa, Eaa, prel + (L*3+0)*4, alpha0, mseg, 0);
    edge_score<<<dim3((Eab*4+255)/256),dim3(256),0,stream>>>(o_b, kt1, ei_ab, Eab, prel + (L*3+1)*4, alpha1, mseg, Na);
    edge_score<<<dim3((Eba*4+255)/256),dim3(256),0,stream>>>(o_a, kt2, ei_ba, Eba, prel + (L*3+2)*4, alpha2, mseg, 0);
    // pass B (exp + segment sum)
    edge_exp<<<dim3((Eaa*4+255)/256),dim3(256),0,stream>>>(ei_aa, Eaa, alpha0, mseg, sseg, 0);
    edge_exp<<<dim3((Eab*4+255)/256),dim3(256),0,stream>>>(ei_ab, Eab, alpha1, mseg, sseg, Na);
    edge_exp<<<dim3((Eba*4+255)/256),dim3(256),0,stream>>>(ei_ba, Eba, alpha2, mseg, sseg, 0);
    // pass C (weighted message scatter)
    edge_agg<<<dim3((Eaa+1)/2),dim3(256),0,stream>>>(ei_aa, Eaa, alpha0, sseg, vt0, agg, 0);
    edge_agg<<<dim3((Eab+1)/2),dim3(256),0,stream>>>(ei_ab, Eab, alpha1, sseg, vt1, agg, Na);
    edge_agg<<<dim3((Eba+1)/2),dim3(256),0,stream>>>(ei_ba, Eba, alpha2, sseg, vt2, agg, 0);
    // finish (gelu -> Wout -> gated skip; gelu inside except L0 where LN comes first)
    int do_gelu = (L == 0) ? 0 : 1;
    finishk<8><<<dim3((Na+7)/8),dim3(128),0,stream>>>(h_a, agg, 0,  Wout + (size_t)(L*2+0)*16384, bout + (L*2+0)*128, skip + L*2+0, do_gelu, Na);
    finishk<8><<<dim3((Nb+7)/8),dim3(128),0,stream>>>(h_b, agg, Na, Wout + (size_t)(L*2+1)*16384, bout + (L*2+1)*128, skip + L*2+1, do_gelu, Nb);
    if (L == 0) {
      ln_gelu<<<dim3((Na+3)/4),dim3(256),0,stream>>>(h_a, ln_g,       ln_b,       Na);
      ln_gelu<<<dim3((Nb+3)/4),dim3(256),0,stream>>>(h_b, ln_g + 128, ln_b + 128, Nb);
    }
  }

  // ---- GAT scorer + SAGPool top-k + MLP ----
  int total = Eaa + Eab + Eba + N;
  gat_x1<<<dim3((N+3)/4),dim3(256),0,stream>>>(hbuf, Wgat, x1buf, N);
  hipMemsetAsync(m1, 0, (size_t)N*sizeof(unsigned), stream);
  hipMemsetAsync(s1, 0, (size_t)N*sizeof(float), stream);
  hipMemsetAsync(score, 0, (size_t)N*sizeof(float), stream);
  gatA<<<dim3((total+255)/256),dim3(256),0,stream>>>(x1buf, ei_aa, ei_ab, ei_ba, Eaa, Eab, Eba, Na, total, att_src, att_dst, esc, m1);
  gatB<<<dim3((total+255)/256),dim3(256),0,stream>>>(ei_aa, ei_ab, ei_ba, Eaa, Eab, Eba, Na, total, esc, m1, s1);
  gatC<<<dim3((total+255)/256),dim3(256),0,stream>>>(ei_aa, ei_ab, ei_ba, Eaa, Eab, Eba, Na, total, esc, s1, x1buf, score);
  int tk_blocks = (N + 255)/256;  // chunk <= 256
  topk_stage1<<<dim3(tk_blocks),dim3(256),0,stream>>>(score, bgat, N, cvals, cidx);
  topk_stage2<<<dim3(1),dim3(256),0,stream>>>(cvals, cidx, tk_blocks*8, valsb, permb);
  mlp_final<<<dim3(1),dim3(256),0,stream>>>(hbuf, valsb, permb, W1, b1, W2, b2, W3, b3, (float*)d_out);
}

// Round 3
// 1187.520 us; speedup vs baseline: 1.9761x; 1.5821x over previous
//
#include <hip/hip_runtime.h>
#include <math.h>

#define HID 128

__device__ __forceinline__ float gelu_f(float x){
  return 0.5f*x*(1.0f+erff(x*0.70710678118654752440f));
}

// o[row, j] = sum_k x[row,k]*W[k,j] + b[j]   (x is nrows x 128, W is 128 x OUT)
template<int OUT, int RPB>
__global__ void rowmm(const float* __restrict__ x, const float* __restrict__ W,
                      const float* __restrict__ b, float* __restrict__ o, int nrows) {
  int t = threadIdx.x;            // 128 threads
  int r0 = blockIdx.x * RPB;
  __shared__ float xs[RPB][128];
  for (int r = 0; r < RPB; r++) {
    int row = r0 + r;
    xs[r][t] = (row < nrows) ? x[(size_t)row*128 + t] : 0.f;
  }
  __syncthreads();
  const int NJ = OUT/128;
  float acc[RPB][NJ] = {};
  for (int k = 0; k < 128; k++) {
    float wv[NJ];
#pragma unroll
    for (int jj = 0; jj < NJ; jj++) wv[jj] = W[(size_t)k*OUT + t + jj*128];
#pragma unroll
    for (int r = 0; r < RPB; r++) {
      float xv = xs[r][k];
#pragma unroll
      for (int jj = 0; jj < NJ; jj++) acc[r][jj] += xv * wv[jj];
    }
  }
  for (int r = 0; r < RPB; r++) {
    int row = r0 + r;
    if (row >= nrows) break;
#pragma unroll
    for (int jj = 0; jj < NJ; jj++)
      o[(size_t)row*OUT + t + jj*128] = acc[r][jj] + b[t + jj*128];
  }
}

// kt[n,h,e] = (sum_d k[n,h,d]*arel[h,d,e]) * prel[h] * inv_sqrt_d   (prel folded!)
// vt[n,h,e] = sum_d v[n,h,d]*mrel[h,d,e]
// o layout: rows of 384, k at +0, v at +256
__global__ void rel_transform(const float* __restrict__ o,
                              const float* __restrict__ arel, const float* __restrict__ mrel,
                              const float* __restrict__ prel,
                              float* __restrict__ kt, float* __restrict__ vt,
                              int n, int rpb) {
  int t = threadIdx.x;            // 128
  int h = t >> 5, e = t & 31;
  float ar[32], mr[32];
#pragma unroll
  for (int d = 0; d < 32; d++) {
    ar[d] = arel[(h*32 + d)*32 + e];
    mr[d] = mrel[(h*32 + d)*32 + e];
  }
  float psc = prel[h] * 0.17677669529663688f;   // prel[h]/sqrt(32)
  __shared__ float ks[128], vs[128];
  int rbeg = blockIdx.x * rpb;
  int rend = rbeg + rpb; if (rend > n) rend = n;
  for (int row = rbeg; row < rend; row++) {
    __syncthreads();
    ks[t] = o[(size_t)row*384 + t];
    vs[t] = o[(size_t)row*384 + 256 + t];
    __syncthreads();
    float ak = 0.f, av = 0.f;
#pragma unroll
    for (int d = 0; d < 32; d++) {
      ak += ks[h*32 + d] * ar[d];
      av += vs[h*32 + d] * mr[d];
    }
    kt[(size_t)row*128 + t] = ak * psc;
    vt[(size_t)row*128 + t] = av;
  }
}

// ---------- CSR build (dst-sorted, shared by all layers + GAT) ----------
// epack: (type<<28) | src_local.  type 0=aa,1=ab,2=ba,3=self-loop.
__global__ void hist_init(int* __restrict__ hist, int N) {
  int i = blockIdx.x*blockDim.x + threadIdx.x;
  if (i < N) hist[i] = 1;   // self loop
}
__global__ void hist_count(const int* __restrict__ ei, int E, int off, int* __restrict__ hist) {
  int i = blockIdx.x*blockDim.x + threadIdx.x;
  if (i < E) atomicAdd(hist + ei[E + i] + off, 1);
}
__global__ void scan_excl(const int* __restrict__ hist, int* __restrict__ roff, int N) {
  __shared__ int part[1024];
  int t = threadIdx.x;
  int chunk = (N + 1023) / 1024;
  int b = t*chunk, e = b + chunk; if (e > N) e = N; if (b > N) b = N;
  int sum = 0;
  for (int i = b; i < e; i++) sum += hist[i];
  part[t] = sum;
  __syncthreads();
  for (int o = 1; o < 1024; o <<= 1) {
    int v = (t >= o) ? part[t - o] : 0;
    __syncthreads();
    part[t] += v;
    __syncthreads();
  }
  int run = (t == 0) ? 0 : part[t - 1];
  for (int i = b; i < e; i++) { roff[i] = run; run += hist[i]; }
  if (t == 1023) roff[N] = run;
}
__global__ void fill_edges(const int* __restrict__ ei, int E, int dstoff, int type,
                           int* __restrict__ cursor, int* __restrict__ epack) {
  int i = blockIdx.x*blockDim.x + threadIdx.x;
  if (i >= E) return;
  int d = ei[E + i] + dstoff;
  int pos = atomicAdd(cursor + d, 1);
  epack[pos] = (type << 28) | ei[i];
}
__global__ void fill_loops(int* __restrict__ cursor, int* __restrict__ epack, int N) {
  int n = blockIdx.x*blockDim.x + threadIdx.x;
  if (n >= N) return;
  int pos = atomicAdd(cursor + n, 1);
  epack[pos] = (3 << 28) | n;
}

// ---------- fused HGT attention: score + online softmax + aggregate ----------
// one wave (64 lanes) per dst node; lane covers dims {lane, lane+64}.
__global__ void seg_attn(const float* __restrict__ o_a, const float* __restrict__ o_b,
                         const float* __restrict__ kt0, const float* __restrict__ kt1,
                         const float* __restrict__ kt2,
                         const float* __restrict__ vt0, const float* __restrict__ vt1,
                         const float* __restrict__ vt2,
                         const int* __restrict__ roff, const int* __restrict__ epack,
                         float* __restrict__ agg, int Na, int N) {
  int wid = (blockIdx.x*blockDim.x + threadIdx.x) >> 6;
  int lane = threadIdx.x & 63;
  if (wid >= N) return;
  int n = wid;
  const float* qrow = (n < Na) ? (o_a + (size_t)n*384 + 128)
                               : (o_b + (size_t)(n - Na)*384 + 128);
  float q0 = qrow[lane], q1 = qrow[lane + 64];
  int beg = roff[n], end = roff[n + 1];
  float m0 = -INFINITY, m1 = -INFINITY, s0 = 0.f, s1 = 0.f, a0 = 0.f, a1 = 0.f;
  for (int i = beg; i < end; i++) {
    int p = epack[i];
    int type = (unsigned)p >> 28;
    if (type == 3) continue;           // self loops belong to GAT only
    int sl = p & 0x0FFFFFFF;
    const float* kb = (type == 0) ? kt0 : (type == 1) ? kt1 : kt2;
    const float* vb = (type == 0) ? vt0 : (type == 1) ? vt1 : vt2;
    const float* kr = kb + (size_t)sl*128;
    const float* vr = vb + (size_t)sl*128;
    float p0 = q0 * kr[lane], p1 = q1 * kr[lane + 64];
#pragma unroll
    for (int o = 16; o; o >>= 1) {      // reduce within 32-lane half (per head)
      p0 += __shfl_xor(p0, o, 64);
      p1 += __shfl_xor(p1, o, 64);
    }
    float v0 = vr[lane], v1 = vr[lane + 64];
    float nm0 = fmaxf(m0, p0), nm1 = fmaxf(m1, p1);
    float sc0 = expf(m0 - nm0), sc1 = expf(m1 - nm1);   // exp(-inf)=0 on first edge
    float e0 = expf(p0 - nm0), e1 = expf(p1 - nm1);
    s0 = s0*sc0 + e0;  a0 = a0*sc0 + e0*v0;  m0 = nm0;
    s1 = s1*sc1 + e1;  a1 = a1*sc1 + e1*v1;  m1 = nm1;
  }
  agg[(size_t)n*128 + lane]      = a0 / (s0 + 1e-16f);
  agg[(size_t)n*128 + 64 + lane] = a1 / (s1 + 1e-16f);
}

// finish: g = gelu(agg_row) @ Wout + bout; v = sig(skip)*g + (1-sig)*x; optionally gelu; in-place on h
template<int RPB>
__global__ void finishk(float* __restrict__ hbuf, const float* __restrict__ agg, int agg_off,
                        const float* __restrict__ Wo, const float* __restrict__ bo,
                        const float* __restrict__ skipp, int do_gelu, int nrows) {
  int t = threadIdx.x;            // 128
  int r0 = blockIdx.x * RPB;
  __shared__ float gs[RPB][128];
  for (int r = 0; r < RPB; r++) {
    int row = r0 + r;
    float a = (row < nrows) ? agg[(size_t)(row + agg_off)*128 + t] : 0.f;
    gs[r][t] = gelu_f(a);
  }
  __syncthreads();
  float acc[RPB] = {};
  for (int k = 0; k < 128; k++) {
    float wv = Wo[(size_t)k*128 + t];
#pragma unroll
    for (int r = 0; r < RPB; r++) acc[r] += gs[r][k]*wv;
  }
  float sg = 1.f/(1.f + expf(-skipp[0]));
  for (int r = 0; r < RPB; r++) {
    int row = r0 + r;
    if (row >= nrows) break;
    float g = acc[r] + bo[t];
    float v = sg*g + (1.f - sg)*hbuf[(size_t)row*128 + t];
    hbuf[(size_t)row*128 + t] = do_gelu ? gelu_f(v) : v;
  }
}

// LayerNorm over 128 then gelu, in place. One wave per row.
__global__ void ln_gelu(float* __restrict__ h, const float* __restrict__ g,
                        const float* __restrict__ b, int nrows) {
  int idx = blockIdx.x*blockDim.x + threadIdx.x;
  int row = idx >> 6, lane = idx & 63;
  if (row >= nrows) return;
  float x0 = h[(size_t)row*128 + lane];
  float x1 = h[(size_t)row*128 + 64 + lane];
  float sum = x0 + x1;
#pragma unroll
  for (int o = 32; o; o >>= 1) sum += __shfl_xor(sum, o, 64);
  float mu = sum * (1.f/128.f);
  float d0 = x0 - mu, d1 = x1 - mu;
  float vs = d0*d0 + d1*d1;
#pragma unroll
  for (int o = 32; o; o >>= 1) vs += __shfl_xor(vs, o, 64);
  float inv = 1.f / sqrtf(vs*(1.f/128.f) + 1e-5f);
  h[(size_t)row*128 + lane]      = gelu_f(d0*inv*g[lane] + b[lane]);
  h[(size_t)row*128 + 64 + lane] = gelu_f(d1*inv*g[64 + lane] + b[64 + lane]);
}

// x1[n] = dot(h[n,:], Wgat[:,0]) — one wave per row
__global__ void gat_x1(const float* __restrict__ h, const float* __restrict__ Wg,
                       float* __restrict__ x1, int N) {
  int idx = blockIdx.x*blockDim.x + threadIdx.x;
  int row = idx >> 6, lane = idx & 63;
  if (row >= N) return;
  float a = h[(size_t)row*128 + lane]*Wg[lane] + h[(size_t)row*128 + 64 + lane]*Wg[64 + lane];
#pragma unroll
  for (int o = 32; o; o >>= 1) a += __shfl_xor(a, o, 64);
  if (lane == 0) x1[row] = a;
}

// fused GAT scorer via CSR: thread per node, online softmax over incident edges (+self loop)
__global__ void gat_all(const float* __restrict__ x1, const int* __restrict__ roff,
                        const int* __restrict__ epack,
                        const float* __restrict__ asrc, const float* __restrict__ adst,
                        int Na, int N, float* __restrict__ score) {
  int n = blockIdx.x*blockDim.x + threadIdx.x;
  if (n >= N) return;
  float xd = x1[n];
  float as_ = asrc[0], ad = adst[0];
  float m = -INFINITY, s = 0.f, acc = 0.f;
  int beg = roff[n], end = roff[n + 1];
  for (int i = beg; i < end; i++) {
    int p = epack[i];
    int type = (unsigned)p >> 28;
    int sl = p & 0x0FFFFFFF;
    int sg = (type == 3) ? n : ((type == 2) ? sl + Na : sl);
    float xs = x1[sg];
    float e = xs*as_ + xd*ad;
    e = (e > 0.f) ? e : 0.2f*e;
    float nm = fmaxf(m, e);
    float sc = expf(m - nm), ee = expf(e - nm);
    s = s*sc + ee;  acc = acc*sc + ee*xs;  m = nm;
  }
  score[n] = acc / (s + 1e-16f);
}

// ---- parallel top-8 ----
__global__ void topk_stage1(const float* __restrict__ score, const float* __restrict__ bgat,
                            int N, float* __restrict__ cvals, int* __restrict__ cidx) {
  __shared__ float bv[256];
  __shared__ int   bi[256];
  int t = threadIdx.x;
  int chunk = (N + gridDim.x - 1) / gridDim.x;   // <= 256 by construction
  int i = blockIdx.x * chunk + t;
  float bg = bgat[0];
  bool valid = (t < chunk && i < N);
  float myv = valid ? score[i] + bg : -INFINITY;
  int   myi = valid ? i : 0x7FFFFFFF;
  for (int k = 0; k < 8; k++) {
    bv[t] = myv; bi[t] = myi;
    __syncthreads();
    for (int o = 128; o; o >>= 1) {
      if (t < o) {
        if (bv[t+o] > bv[t] || (bv[t+o] == bv[t] && bi[t+o] < bi[t])) { bv[t]=bv[t+o]; bi[t]=bi[t+o]; }
      }
      __syncthreads();
    }
    if (t == 0) { cvals[blockIdx.x*8 + k] = bv[0]; cidx[blockIdx.x*8 + k] = bi[0]; }
    if (myi == bi[0]) myv = -INFINITY;   // pop winner
    __syncthreads();
  }
}

__global__ void topk_stage2(const float* __restrict__ cvals, const int* __restrict__ cidx,
                            int C, float* __restrict__ vals, int* __restrict__ perm) {
  __shared__ float bv[256];
  __shared__ int   bi[256];
  __shared__ int   seli[8];
  int t = threadIdx.x;
  for (int k = 0; k < 8; k++) {
    float best = -INFINITY; int besti = 0x7FFFFFFF;
    for (int i = t; i < C; i += 256) {
      int id = cidx[i];
      bool taken = false;
      for (int j = 0; j < k; j++) if (seli[j] == id) taken = true;
      if (taken) continue;
      float v = cvals[i];
      if (v > best || (v == best && id < besti)) { best = v; besti = id; }
    }
    bv[t] = best; bi[t] = besti;
    __syncthreads();
    for (int o = 128; o; o >>= 1) {
      if (t < o) {
        if (bv[t+o] > bv[t] || (bv[t+o] == bv[t] && bi[t+o] < bi[t])) { bv[t]=bv[t+o]; bi[t]=bi[t+o]; }
      }
      __syncthreads();
    }
    if (t == 0) { seli[k] = bi[0]; vals[k] = bv[0]; perm[k] = bi[0]; }
    __syncthreads();
  }
}

__global__ void mlp_final(const float* __restrict__ h, const float* __restrict__ vals,
                          const int* __restrict__ perm,
                          const float* __restrict__ W1, const float* __restrict__ b1,
                          const float* __restrict__ W2, const float* __restrict__ b2,
                          const float* __restrict__ W3, const float* __restrict__ b3,
                          float* __restrict__ out) {
  __shared__ float hp[1024], v1[128], v2[64];
  int t = threadIdx.x;  // 256
  for (int i = t; i < 1024; i += 256) {
    int r = i >> 7, d = i & 127;
    hp[i] = h[(size_t)perm[r]*128 + d] * tanhf(vals[r]);
  }
  __syncthreads();
  if (t < 128) {
    float a = 0.f;
    for (int k = 0; k < 1024; k++) a += hp[k]*W1[(size_t)k*128 + t];
    v1[t] = gelu_f(a + b1[t]);
  }
  __syncthreads();
  if (t < 64) {
    float a = 0.f;
    for (int k = 0; k < 128; k++) a += v1[k]*W2[(size_t)k*64 + t];
    v2[t] = gelu_f(a + b2[t]);
  }
  __syncthreads();
  if (t < 16) {
    float a = 0.f;
    for (int k = 0; k < 64; k++) a += v2[k]*W3[(size_t)k*16 + t];
    float r = gelu_f(a + b3[t]);
    if (isnan(r)) r = 0.f;
    else if (isinf(r)) r = (r > 0.f) ? 3.4028234663852886e38f : -3.4028234663852886e38f;
    out[t] = r;
  }
}

extern "C" void kernel_launch(void* const* d_in, const int* in_sizes, int n_in,
                              void* d_out, int out_size, void* d_ws, size_t ws_size,
                              hipStream_t stream) {
  const float* x_a  = (const float*)d_in[0];
  const float* x_b  = (const float*)d_in[1];
  const int* ei_aa  = (const int*)d_in[2];
  const int* ei_ab  = (const int*)d_in[3];
  const int* ei_ba  = (const int*)d_in[4];
  const float* Wkqv = (const float*)d_in[5];
  const float* bkqv = (const float*)d_in[6];
  const float* Wout = (const float*)d_in[7];
  const float* bout = (const float*)d_in[8];
  const float* skip = (const float*)d_in[9];
  const float* arel = (const float*)d_in[10];
  const float* mrel = (const float*)d_in[11];
  const float* prel = (const float*)d_in[12];
  const float* ln_g = (const float*)d_in[13];
  const float* ln_b = (const float*)d_in[14];
  const float* Wgat = (const float*)d_in[15];
  const float* att_src = (const float*)d_in[16];
  const float* att_dst = (const float*)d_in[17];
  const float* bgat = (const float*)d_in[18];
  const float* W1 = (const float*)d_in[19];
  const float* b1 = (const float*)d_in[20];
  const float* W2 = (const float*)d_in[21];
  const float* b2 = (const float*)d_in[22];
  const float* W3 = (const float*)d_in[23];
  const float* b3 = (const float*)d_in[24];

  int Na = in_sizes[0]/128, Nb = in_sizes[1]/128, N = Na + Nb;
  int Eaa = in_sizes[2]/2, Eab = in_sizes[3]/2, Eba = in_sizes[4]/2;
  int M = Eaa + Eab + Eba + N;   // CSR slots incl. self loops

  // workspace layout
  float* w = (float*)d_ws;
  size_t off = 0;
  auto alloc = [&](size_t n) { float* p = w + off; off += n; return p; };
  float* hbuf = alloc((size_t)N*128);
  float* o_a  = alloc((size_t)Na*384);
  float* o_b  = alloc((size_t)Nb*384);
  float* kt0  = alloc((size_t)Na*128);
  float* kt1  = alloc((size_t)Na*128);
  float* kt2  = alloc((size_t)Nb*128);
  float* vt0  = alloc((size_t)Na*128);
  float* vt1  = alloc((size_t)Na*128);
  float* vt2  = alloc((size_t)Nb*128);
  float* agg   = alloc((size_t)N*128);
  float* x1buf = alloc((size_t)N);
  float* score = alloc((size_t)N);
  float* valsb = alloc(8);
  int*   permb = (int*)alloc(8);
  float* cvals = alloc(2048);
  int*   cidx  = (int*)alloc(2048);
  int*   hist  = (int*)alloc((size_t)N);
  int*   roff  = (int*)alloc((size_t)N + 1);
  int*   cursor= (int*)alloc((size_t)N);
  int*   epack = (int*)alloc((size_t)M);

  float* h_a = hbuf;
  float* h_b = hbuf + (size_t)Na*128;

  hipMemcpyAsync(h_a, x_a, (size_t)Na*128*sizeof(float), hipMemcpyDeviceToDevice, stream);
  hipMemcpyAsync(h_b, x_b, (size_t)Nb*128*sizeof(float), hipMemcpyDeviceToDevice, stream);

  // ---- build dst-sorted CSR once (shared by all 3 layers + GAT) ----
  hist_init<<<dim3((N+255)/256),dim3(256),0,stream>>>(hist, N);
  hist_count<<<dim3((Eaa+255)/256),dim3(256),0,stream>>>(ei_aa, Eaa, 0,  hist);
  hist_count<<<dim3((Eab+255)/256),dim3(256),0,stream>>>(ei_ab, Eab, Na, hist);
  hist_count<<<dim3((Eba+255)/256),dim3(256),0,stream>>>(ei_ba, Eba, 0,  hist);
  scan_excl<<<dim3(1),dim3(1024),0,stream>>>(hist, roff, N);
  hipMemcpyAsync(cursor, roff, (size_t)N*sizeof(int), hipMemcpyDeviceToDevice, stream);
  fill_edges<<<dim3((Eaa+255)/256),dim3(256),0,stream>>>(ei_aa, Eaa, 0,  0, cursor, epack);
  fill_edges<<<dim3((Eab+255)/256),dim3(256),0,stream>>>(ei_ab, Eab, Na, 1, cursor, epack);
  fill_edges<<<dim3((Eba+255)/256),dim3(256),0,stream>>>(ei_ba, Eba, 0,  2, cursor, epack);
  fill_loops<<<dim3((N+255)/256),dim3(256),0,stream>>>(cursor, epack, N);

  const int RPB = 8;
  int rel_rpb_a = (Na + 1023)/1024, rel_rpb_b = (Nb + 1023)/1024;

  for (int L = 0; L < 3; L++) {
    rowmm<384,8><<<dim3((Na+RPB-1)/RPB),dim3(128),0,stream>>>(h_a, Wkqv + (size_t)(L*2+0)*128*384, bkqv + (L*2+0)*384, o_a, Na);
    rowmm<384,8><<<dim3((Nb+RPB-1)/RPB),dim3(128),0,stream>>>(h_b, Wkqv + (size_t)(L*2+1)*128*384, bkqv + (L*2+1)*384, o_b, Nb);
    rel_transform<<<dim3(1024),dim3(128),0,stream>>>(o_a, arel + (size_t)(L*3+0)*4096, mrel + (size_t)(L*3+0)*4096, prel + (L*3+0)*4, kt0, vt0, Na, rel_rpb_a);
    rel_transform<<<dim3(1024),dim3(128),0,stream>>>(o_a, arel + (size_t)(L*3+1)*4096, mrel + (size_t)(L*3+1)*4096, prel + (L*3+1)*4, kt1, vt1, Na, rel_rpb_a);
    rel_transform<<<dim3(1024),dim3(128),0,stream>>>(o_b, arel + (size_t)(L*3+2)*4096, mrel + (size_t)(L*3+2)*4096, prel + (L*3+2)*4, kt2, vt2, Nb, rel_rpb_b);
    // fused attention: score + softmax + aggregate, gather via CSR, no atomics
    seg_attn<<<dim3((N+3)/4),dim3(256),0,stream>>>(o_a, o_b, kt0, kt1, kt2, vt0, vt1, vt2,
                                                   roff, epack, agg, Na, N);
    int do_gelu = (L == 0) ? 0 : 1;
    finishk<8><<<dim3((Na+7)/8),dim3(128),0,stream>>>(h_a, agg, 0,  Wout + (size_t)(L*2+0)*16384, bout + (L*2+0)*128, skip + L*2+0, do_gelu, Na);
    finishk<8><<<dim3((Nb+7)/8),dim3(128),0,stream>>>(h_b, agg, Na, Wout + (size_t)(L*2+1)*16384, bout + (L*2+1)*128, skip + L*2+1, do_gelu, Nb);
    if (L == 0) {
      ln_gelu<<<dim3((Na+3)/4),dim3(256),0,stream>>>(h_a, ln_g,       ln_b,       Na);
      ln_gelu<<<dim3((Nb+3)/4),dim3(256),0,stream>>>(h_b, ln_g + 128, ln_b + 128, Nb);
    }
  }

  // ---- GAT scorer + SAGPool top-k + MLP ----
  gat_x1<<<dim3((N+3)/4),dim3(256),0,stream>>>(hbuf, Wgat, x1buf, N);
  gat_all<<<dim3((N+255)/256),dim3(256),0,stream>>>(x1buf, roff, epack, att_src, att_dst, Na, N, score);
  int tk_blocks = (N + 255)/256;
  topk_stage1<<<dim3(tk_blocks),dim3(256),0,stream>>>(score, bgat, N, cvals, cidx);
  topk_stage2<<<dim3(1),dim3(256),0,stream>>>(cvals, cidx, tk_blocks*8, valsb, permb);
  mlp_final<<<dim3(1),dim3(256),0,stream>>>(hbuf, valsb, permb, W1, b1, W2, b2, W3, b3, (float*)d_out);
}

// Round 4
// 1151.101 us; speedup vs baseline: 2.0386x; 1.0316x over previous
//
#include <hip/hip_runtime.h>
#include <math.h>

#define HID 128

__device__ __forceinline__ float gelu_f(float x){
  return 0.5f*x*(1.0f+erff(x*0.70710678118654752440f));
}

// o[row, j] = sum_k x[row,k]*W[k,j] + b[j]   (x is nrows x 128, W is 128 x OUT)
template<int OUT, int RPB>
__global__ void rowmm(const float* __restrict__ x, const float* __restrict__ W,
                      const float* __restrict__ b, float* __restrict__ o, int nrows) {
  int t = threadIdx.x;            // 128 threads
  int r0 = blockIdx.x * RPB;
  __shared__ float xs[RPB][128];
  for (int r = 0; r < RPB; r++) {
    int row = r0 + r;
    xs[r][t] = (row < nrows) ? x[(size_t)row*128 + t] : 0.f;
  }
  __syncthreads();
  const int NJ = OUT/128;
  float acc[RPB][NJ] = {};
  for (int k = 0; k < 128; k++) {
    float wv[NJ];
#pragma unroll
    for (int jj = 0; jj < NJ; jj++) wv[jj] = W[(size_t)k*OUT + t + jj*128];
#pragma unroll
    for (int r = 0; r < RPB; r++) {
      float xv = xs[r][k];
#pragma unroll
      for (int jj = 0; jj < NJ; jj++) acc[r][jj] += xv * wv[jj];
    }
  }
  for (int r = 0; r < RPB; r++) {
    int row = r0 + r;
    if (row >= nrows) break;
#pragma unroll
    for (int jj = 0; jj < NJ; jj++)
      o[(size_t)row*OUT + t + jj*128] = acc[r][jj] + b[t + jj*128];
  }
}

// ktv layout per node: [h][0..31] = k-transformed * prel/sqrt(d) * log2(e),
//                      [h][32..63] = v-transformed.   256 floats (1KB) per node.
// o layout: rows of 384, k at +0, v at +256
__global__ void rel_transform(const float* __restrict__ o,
                              const float* __restrict__ arel, const float* __restrict__ mrel,
                              const float* __restrict__ prel,
                              float* __restrict__ ktv,
                              int n, int rpb) {
  int t = threadIdx.x;            // 128
  int h = t >> 5, e = t & 31;
  float ar[32], mr[32];
#pragma unroll
  for (int d = 0; d < 32; d++) {
    ar[d] = arel[(h*32 + d)*32 + e];
    mr[d] = mrel[(h*32 + d)*32 + e];
  }
  // prel[h]/sqrt(32) * log2(e)  (exp2-domain softmax)
  float psc = prel[h] * 0.17677669529663688f * 1.4426950408889634f;
  __shared__ float ks[128], vs[128];
  int rbeg = blockIdx.x * rpb;
  int rend = rbeg + rpb; if (rend > n) rend = n;
  for (int row = rbeg; row < rend; row++) {
    __syncthreads();
    ks[t] = o[(size_t)row*384 + t];
    vs[t] = o[(size_t)row*384 + 256 + t];
    __syncthreads();
    float ak = 0.f, av = 0.f;
#pragma unroll
    for (int d = 0; d < 32; d++) {
      ak += ks[h*32 + d] * ar[d];
      av += vs[h*32 + d] * mr[d];
    }
    ktv[(size_t)row*256 + h*64 + e]      = ak * psc;
    ktv[(size_t)row*256 + h*64 + 32 + e] = av;
  }
}

// ---------- CSR build (dst-sorted, shared by all layers + GAT) ----------
// epack: (type<<28) | src_local.  type 0=aa,1=ab,2=ba,3=self-loop.
__global__ void hist_init(int* __restrict__ hist, int N) {
  int i = blockIdx.x*blockDim.x + threadIdx.x;
  if (i < N) hist[i] = 1;   // self loop
}
__global__ void hist_count(const int* __restrict__ ei, int E, int off, int* __restrict__ hist) {
  int i = blockIdx.x*blockDim.x + threadIdx.x;
  if (i < E) atomicAdd(hist + ei[E + i] + off, 1);
}
__global__ void scan_excl(const int* __restrict__ hist, int* __restrict__ roff, int N) {
  __shared__ int part[1024];
  int t = threadIdx.x;
  int chunk = (N + 1023) / 1024;
  int b = t*chunk, e = b + chunk; if (e > N) e = N; if (b > N) b = N;
  int sum = 0;
  for (int i = b; i < e; i++) sum += hist[i];
  part[t] = sum;
  __syncthreads();
  for (int o = 1; o < 1024; o <<= 1) {
    int v = (t >= o) ? part[t - o] : 0;
    __syncthreads();
    part[t] += v;
    __syncthreads();
  }
  int run = (t == 0) ? 0 : part[t - 1];
  for (int i = b; i < e; i++) { roff[i] = run; run += hist[i]; }
  if (t == 1023) roff[N] = run;
}
__global__ void fill_edges(const int* __restrict__ ei, int E, int dstoff, int type,
                           int* __restrict__ cursor, int* __restrict__ epack) {
  int i = blockIdx.x*blockDim.x + threadIdx.x;
  if (i >= E) return;
  int d = ei[E + i] + dstoff;
  int pos = atomicAdd(cursor + d, 1);
  epack[pos] = (type << 28) | ei[i];
}
__global__ void fill_loops(int* __restrict__ cursor, int* __restrict__ epack, int N) {
  int n = blockIdx.x*blockDim.x + threadIdx.x;
  if (n >= N) return;
  int pos = atomicAdd(cursor + n, 1);
  epack[pos] = (3 << 28) | n;
}

// ---------- fused HGT attention: score + online softmax (base-2) + aggregate ----------
// one wave per dst node; quarter-wave (16 lanes) per head, 2 dims per lane.
__global__ void seg_attn(const float* __restrict__ o_a, const float* __restrict__ o_b,
                         const float* __restrict__ ktv0, const float* __restrict__ ktv1,
                         const float* __restrict__ ktv2,
                         const int* __restrict__ roff, const int* __restrict__ epack,
                         float* __restrict__ agg, int Na, int N) {
  int wid = (blockIdx.x*blockDim.x + threadIdx.x) >> 6;
  int lane = threadIdx.x & 63;
  if (wid >= N) return;
  int h = lane >> 4;            // head
  int d0 = (lane & 15) * 2;     // dims d0, d0+1 of head h
  const float* qrow = (wid < Na) ? (o_a + (size_t)wid*384 + 128)
                                 : (o_b + (size_t)(wid - Na)*384 + 128);
  float q0 = qrow[h*32 + d0], q1 = qrow[h*32 + d0 + 1];
  int beg = roff[wid], end = roff[wid + 1];
  float m = -INFINITY, s = 0.f, a0 = 0.f, a1 = 0.f;
  for (int i = beg; i < end; i++) {
    int p = epack[i];
    unsigned type = (unsigned)p >> 28;
    if (type == 3) continue;    // self loops belong to GAT only
    int sl = p & 0x0FFFFFFF;
    const float* base = (type == 0) ? ktv0 : (type == 1) ? ktv1 : ktv2;
    const float* kp = base + (size_t)sl*256 + h*64 + d0;
    float2 kv = *(const float2*)kp;
    float2 vv = *(const float2*)(kp + 32);
    float sc = q0*kv.x + q1*kv.y;
    sc += __shfl_xor(sc, 1, 64);
    sc += __shfl_xor(sc, 2, 64);
    sc += __shfl_xor(sc, 4, 64);
    sc += __shfl_xor(sc, 8, 64);   // sc uniform within quarter = this head's score (base-2 scaled)
    float nm = fmaxf(m, sc);
    float scale = exp2f(m - nm);   // first edge: exp2(-inf) = 0
    float e = exp2f(sc - nm);
    s  = s*scale  + e;
    a0 = a0*scale + e*vv.x;
    a1 = a1*scale + e*vv.y;
    m = nm;
  }
  float inv = 1.f / (s + 1e-16f);
  float2 o2; o2.x = a0*inv; o2.y = a1*inv;
  *(float2*)(agg + (size_t)wid*128 + h*32 + d0) = o2;
}

// finish: g = gelu(agg_row) @ Wout + bout; v = sig(skip)*g + (1-sig)*x; optionally gelu; in-place on h
template<int RPB>
__global__ void finishk(float* __restrict__ hbuf, const float* __restrict__ agg, int agg_off,
                        const float* __restrict__ Wo, const float* __restrict__ bo,
                        const float* __restrict__ skipp, int do_gelu, int nrows) {
  int t = threadIdx.x;            // 128
  int r0 = blockIdx.x * RPB;
  __shared__ float gs[RPB][128];
  for (int r = 0; r < RPB; r++) {
    int row = r0 + r;
    float a = (row < nrows) ? agg[(size_t)(row + agg_off)*128 + t] : 0.f;
    gs[r][t] = gelu_f(a);
  }
  __syncthreads();
  float acc[RPB] = {};
  for (int k = 0; k < 128; k++) {
    float wv = Wo[(size_t)k*128 + t];
#pragma unroll
    for (int r = 0; r < RPB; r++) acc[r] += gs[r][k]*wv;
  }
  float sg = 1.f/(1.f + expf(-skipp[0]));
  for (int r = 0; r < RPB; r++) {
    int row = r0 + r;
    if (row >= nrows) break;
    float g = acc[r] + bo[t];
    float v = sg*g + (1.f - sg)*hbuf[(size_t)row*128 + t];
    hbuf[(size_t)row*128 + t] = do_gelu ? gelu_f(v) : v;
  }
}

// LayerNorm over 128 then gelu, in place. One wave per row.
__global__ void ln_gelu(float* __restrict__ h, const float* __restrict__ g,
                        const float* __restrict__ b, int nrows) {
  int idx = blockIdx.x*blockDim.x + threadIdx.x;
  int row = idx >> 6, lane = idx & 63;
  if (row >= nrows) return;
  float x0 = h[(size_t)row*128 + lane];
  float x1 = h[(size_t)row*128 + 64 + lane];
  float sum = x0 + x1;
#pragma unroll
  for (int o = 32; o; o >>= 1) sum += __shfl_xor(sum, o, 64);
  float mu = sum * (1.f/128.f);
  float d0 = x0 - mu, d1 = x1 - mu;
  float vs = d0*d0 + d1*d1;
#pragma unroll
  for (int o = 32; o; o >>= 1) vs += __shfl_xor(vs, o, 64);
  float inv = 1.f / sqrtf(vs*(1.f/128.f) + 1e-5f);
  h[(size_t)row*128 + lane]      = gelu_f(d0*inv*g[lane] + b[lane]);
  h[(size_t)row*128 + 64 + lane] = gelu_f(d1*inv*g[64 + lane] + b[64 + lane]);
}

// x1[n] = dot(h[n,:], Wgat[:,0]) — one wave per row
__global__ void gat_x1(const float* __restrict__ h, const float* __restrict__ Wg,
                       float* __restrict__ x1, int N) {
  int idx = blockIdx.x*blockDim.x + threadIdx.x;
  int row = idx >> 6, lane = idx & 63;
  if (row >= N) return;
  float a = h[(size_t)row*128 + lane]*Wg[lane] + h[(size_t)row*128 + 64 + lane]*Wg[64 + lane];
#pragma unroll
  for (int o = 32; o; o >>= 1) a += __shfl_xor(a, o, 64);
  if (lane == 0) x1[row] = a;
}

// fused GAT scorer via CSR: thread per node, online softmax over incident edges (+self loop)
__global__ void gat_all(const float* __restrict__ x1, const int* __restrict__ roff,
                        const int* __restrict__ epack,
                        const float* __restrict__ asrc, const float* __restrict__ adst,
                        int Na, int N, float* __restrict__ score) {
  int n = blockIdx.x*blockDim.x + threadIdx.x;
  if (n >= N) return;
  float xd = x1[n];
  float as_ = asrc[0], ad = adst[0];
  float m = -INFINITY, s = 0.f, acc = 0.f;
  int beg = roff[n], end = roff[n + 1];
  for (int i = beg; i < end; i++) {
    int p = epack[i];
    int type = (unsigned)p >> 28;
    int sl = p & 0x0FFFFFFF;
    int sg = (type == 3) ? n : ((type == 2) ? sl + Na : sl);
    float xs = x1[sg];
    float e = xs*as_ + xd*ad;
    e = (e > 0.f) ? e : 0.2f*e;
    float nm = fmaxf(m, e);
    float sc = __expf(m - nm), ee = __expf(e - nm);
    s = s*sc + ee;  acc = acc*sc + ee*xs;  m = nm;
  }
  score[n] = acc / (s + 1e-16f);
}

// ---- parallel top-8 ----
__global__ void topk_stage1(const float* __restrict__ score, const float* __restrict__ bgat,
                            int N, float* __restrict__ cvals, int* __restrict__ cidx) {
  __shared__ float bv[256];
  __shared__ int   bi[256];
  int t = threadIdx.x;
  int chunk = (N + gridDim.x - 1) / gridDim.x;   // <= 256 by construction
  int i = blockIdx.x * chunk + t;
  float bg = bgat[0];
  bool valid = (t < chunk && i < N);
  float myv = valid ? score[i] + bg : -INFINITY;
  int   myi = valid ? i : 0x7FFFFFFF;
  for (int k = 0; k < 8; k++) {
    bv[t] = myv; bi[t] = myi;
    __syncthreads();
    for (int o = 128; o; o >>= 1) {
      if (t < o) {
        if (bv[t+o] > bv[t] || (bv[t+o] == bv[t] && bi[t+o] < bi[t])) { bv[t]=bv[t+o]; bi[t]=bi[t+o]; }
      }
      __syncthreads();
    }
    if (t == 0) { cvals[blockIdx.x*8 + k] = bv[0]; cidx[blockIdx.x*8 + k] = bi[0]; }
    if (myi == bi[0]) myv = -INFINITY;   // pop winner
    __syncthreads();
  }
}

__global__ void topk_stage2(const float* __restrict__ cvals, const int* __restrict__ cidx,
                            int C, float* __restrict__ vals, int* __restrict__ perm) {
  __shared__ float bv[256];
  __shared__ int   bi[256];
  __shared__ int   seli[8];
  int t = threadIdx.x;
  for (int k = 0; k < 8; k++) {
    float best = -INFINITY; int besti = 0x7FFFFFFF;
    for (int i = t; i < C; i += 256) {
      int id = cidx[i];
      bool taken = false;
      for (int j = 0; j < k; j++) if (seli[j] == id) taken = true;
      if (taken) continue;
      float v = cvals[i];
      if (v > best || (v == best && id < besti)) { best = v; besti = id; }
    }
    bv[t] = best; bi[t] = besti;
    __syncthreads();
    for (int o = 128; o; o >>= 1) {
      if (t < o) {
        if (bv[t+o] > bv[t] || (bv[t+o] == bv[t] && bi[t+o] < bi[t])) { bv[t]=bv[t+o]; bi[t]=bi[t+o]; }
      }
      __syncthreads();
    }
    if (t == 0) { seli[k] = bi[0]; vals[k] = bv[0]; perm[k] = bi[0]; }
    __syncthreads();
  }
}

__global__ void mlp_final(const float* __restrict__ h, const float* __restrict__ vals,
                          const int* __restrict__ perm,
                          const float* __restrict__ W1, const float* __restrict__ b1,
                          const float* __restrict__ W2, const float* __restrict__ b2,
                          const float* __restrict__ W3, const float* __restrict__ b3,
                          float* __restrict__ out) {
  __shared__ float hp[1024], v1[128], v2[64];
  int t = threadIdx.x;  // 256
  for (int i = t; i < 1024; i += 256) {
    int r = i >> 7, d = i & 127;
    hp[i] = h[(size_t)perm[r]*128 + d] * tanhf(vals[r]);
  }
  __syncthreads();
  if (t < 128) {
    float a = 0.f;
    for (int k = 0; k < 1024; k++) a += hp[k]*W1[(size_t)k*128 + t];
    v1[t] = gelu_f(a + b1[t]);
  }
  __syncthreads();
  if (t < 64) {
    float a = 0.f;
    for (int k = 0; k < 128; k++) a += v1[k]*W2[(size_t)k*64 + t];
    v2[t] = gelu_f(a + b2[t]);
  }
  __syncthreads();
  if (t < 16) {
    float a = 0.f;
    for (int k = 0; k < 64; k++) a += v2[k]*W3[(size_t)k*16 + t];
    float r = gelu_f(a + b3[t]);
    if (isnan(r)) r = 0.f;
    else if (isinf(r)) r = (r > 0.f) ? 3.4028234663852886e38f : -3.4028234663852886e38f;
    out[t] = r;
  }
}

extern "C" void kernel_launch(void* const* d_in, const int* in_sizes, int n_in,
                              void* d_out, int out_size, void* d_ws, size_t ws_size,
                              hipStream_t stream) {
  const float* x_a  = (const float*)d_in[0];
  const float* x_b  = (const float*)d_in[1];
  const int* ei_aa  = (const int*)d_in[2];
  const int* ei_ab  = (const int*)d_in[3];
  const int* ei_ba  = (const int*)d_in[4];
  const float* Wkqv = (const float*)d_in[5];
  const float* bkqv = (const float*)d_in[6];
  const float* Wout = (const float*)d_in[7];
  const float* bout = (const float*)d_in[8];
  const float* skip = (const float*)d_in[9];
  const float* arel = (const float*)d_in[10];
  const float* mrel = (const float*)d_in[11];
  const float* prel = (const float*)d_in[12];
  const float* ln_g = (const float*)d_in[13];
  const float* ln_b = (const float*)d_in[14];
  const float* Wgat = (const float*)d_in[15];
  const float* att_src = (const float*)d_in[16];
  const float* att_dst = (const float*)d_in[17];
  const float* bgat = (const float*)d_in[18];
  const float* W1 = (const float*)d_in[19];
  const float* b1 = (const float*)d_in[20];
  const float* W2 = (const float*)d_in[21];
  const float* b2 = (const float*)d_in[22];
  const float* W3 = (const float*)d_in[23];
  const float* b3 = (const float*)d_in[24];

  int Na = in_sizes[0]/128, Nb = in_sizes[1]/128, N = Na + Nb;
  int Eaa = in_sizes[2]/2, Eab = in_sizes[3]/2, Eba = in_sizes[4]/2;
  int M = Eaa + Eab + Eba + N;   // CSR slots incl. self loops

  // workspace layout
  float* w = (float*)d_ws;
  size_t off = 0;
  auto alloc = [&](size_t n) { float* p = w + off; off += n; return p; };
  float* hbuf = alloc((size_t)N*128);
  float* o_a  = alloc((size_t)Na*384);
  float* o_b  = alloc((size_t)Nb*384);
  float* ktv0 = alloc((size_t)Na*256);
  float* ktv1 = alloc((size_t)Na*256);
  float* ktv2 = alloc((size_t)Nb*256);
  float* agg   = alloc((size_t)N*128);
  float* x1buf = alloc((size_t)N);
  float* score = alloc((size_t)N);
  float* valsb = alloc(8);
  int*   permb = (int*)alloc(8);
  float* cvals = alloc(2048);
  int*   cidx  = (int*)alloc(2048);
  int*   hist  = (int*)alloc((size_t)N);
  int*   roff  = (int*)alloc((size_t)N + 1);
  int*   cursor= (int*)alloc((size_t)N);
  int*   epack = (int*)alloc((size_t)M);

  float* h_a = hbuf;
  float* h_b = hbuf + (size_t)Na*128;

  hipMemcpyAsync(h_a, x_a, (size_t)Na*128*sizeof(float), hipMemcpyDeviceToDevice, stream);
  hipMemcpyAsync(h_b, x_b, (size_t)Nb*128*sizeof(float), hipMemcpyDeviceToDevice, stream);

  // ---- build dst-sorted CSR once (shared by all 3 layers + GAT) ----
  hist_init<<<dim3((N+255)/256),dim3(256),0,stream>>>(hist, N);
  hist_count<<<dim3((Eaa+255)/256),dim3(256),0,stream>>>(ei_aa, Eaa, 0,  hist);
  hist_count<<<dim3((Eab+255)/256),dim3(256),0,stream>>>(ei_ab, Eab, Na, hist);
  hist_count<<<dim3((Eba+255)/256),dim3(256),0,stream>>>(ei_ba, Eba, 0,  hist);
  scan_excl<<<dim3(1),dim3(1024),0,stream>>>(hist, roff, N);
  hipMemcpyAsync(cursor, roff, (size_t)N*sizeof(int), hipMemcpyDeviceToDevice, stream);
  fill_edges<<<dim3((Eaa+255)/256),dim3(256),0,stream>>>(ei_aa, Eaa, 0,  0, cursor, epack);
  fill_edges<<<dim3((Eab+255)/256),dim3(256),0,stream>>>(ei_ab, Eab, Na, 1, cursor, epack);
  fill_edges<<<dim3((Eba+255)/256),dim3(256),0,stream>>>(ei_ba, Eba, 0,  2, cursor, epack);
  fill_loops<<<dim3((N+255)/256),dim3(256),0,stream>>>(cursor, epack, N);

  const int RPB = 8;
  int rel_rpb_a = (Na + 1023)/1024, rel_rpb_b = (Nb + 1023)/1024;

  for (int L = 0; L < 3; L++) {
    rowmm<384,8><<<dim3((Na+RPB-1)/RPB),dim3(128),0,stream>>>(h_a, Wkqv + (size_t)(L*2+0)*128*384, bkqv + (L*2+0)*384, o_a, Na);
    rowmm<384,8><<<dim3((Nb+RPB-1)/RPB),dim3(128),0,stream>>>(h_b, Wkqv + (size_t)(L*2+1)*128*384, bkqv + (L*2+1)*384, o_b, Nb);
    rel_transform<<<dim3(1024),dim3(128),0,stream>>>(o_a, arel + (size_t)(L*3+0)*4096, mrel + (size_t)(L*3+0)*4096, prel + (L*3+0)*4, ktv0, Na, rel_rpb_a);
    rel_transform<<<dim3(1024),dim3(128),0,stream>>>(o_a, arel + (size_t)(L*3+1)*4096, mrel + (size_t)(L*3+1)*4096, prel + (L*3+1)*4, ktv1, Na, rel_rpb_a);
    rel_transform<<<dim3(1024),dim3(128),0,stream>>>(o_b, arel + (size_t)(L*3+2)*4096, mrel + (size_t)(L*3+2)*4096, prel + (L*3+2)*4, ktv2, Nb, rel_rpb_b);
    // fused attention: score + softmax + aggregate, gather via CSR, no atomics
    seg_attn<<<dim3((N+3)/4),dim3(256),0,stream>>>(o_a, o_b, ktv0, ktv1, ktv2,
                                                   roff, epack, agg, Na, N);
    int do_gelu = (L == 0) ? 0 : 1;
    finishk<8><<<dim3((Na+7)/8),dim3(128),0,stream>>>(h_a, agg, 0,  Wout + (size_t)(L*2+0)*16384, bout + (L*2+0)*128, skip + L*2+0, do_gelu, Na);
    finishk<8><<<dim3((Nb+7)/8),dim3(128),0,stream>>>(h_b, agg, Na, Wout + (size_t)(L*2+1)*16384, bout + (L*2+1)*128, skip + L*2+1, do_gelu, Nb);
    if (L == 0) {
      ln_gelu<<<dim3((Na+3)/4),dim3(256),0,stream>>>(h_a, ln_g,       ln_b,       Na);
      ln_gelu<<<dim3((Nb+3)/4),dim3(256),0,stream>>>(h_b, ln_g + 128, ln_b + 128, Nb);
    }
  }

  // ---- GAT scorer + SAGPool top-k + MLP ----
  gat_x1<<<dim3((N+3)/4),dim3(256),0,stream>>>(hbuf, Wgat, x1buf, N);
  gat_all<<<dim3((N+255)/256),dim3(256),0,stream>>>(x1buf, roff, epack, att_src, att_dst, Na, N, score);
  int tk_blocks = (N + 255)/256;
  topk_stage1<<<dim3(tk_blocks),dim3(256),0,stream>>>(score, bgat, N, cvals, cidx);
  topk_stage2<<<dim3(1),dim3(256),0,stream>>>(cvals, cidx, tk_blocks*8, valsb, permb);
  mlp_final<<<dim3(1),dim3(256),0,stream>>>(hbuf, valsb, permb, W1, b1, W2, b2, W3, b3, (float*)d_out);
}

// Round 5
// 975.221 us; speedup vs baseline: 2.4063x; 1.1803x over previous
//
#include <hip/hip_runtime.h>
#include <math.h>

#define HID 128

__device__ __forceinline__ float gelu_f(float x){
  return 0.5f*x*(1.0f+erff(x*0.70710678118654752440f));
}

// ---- fused KQV GEMM for both node types ----
// o[row, j] = sum_k x[row,k]*W[k,j] + b[j]   (x is nrows x 128, W is 128 x 384)
template<int RPB>
__global__ void rowmm2(const float* __restrict__ xa, const float* __restrict__ xb,
                       const float* __restrict__ Wa, const float* __restrict__ Wb,
                       const float* __restrict__ ba_, const float* __restrict__ bb_,
                       float* __restrict__ oa, float* __restrict__ ob, int Na, int Nb) {
  const int OUT = 384;
  int nba = (Na + RPB - 1)/RPB;
  const float *x, *W, *b; float* o; int nrows, r0;
  if ((int)blockIdx.x < nba) { x=xa; W=Wa; b=ba_; o=oa; nrows=Na; r0=blockIdx.x*RPB; }
  else { x=xb; W=Wb; b=bb_; o=ob; nrows=Nb; r0=(blockIdx.x-nba)*RPB; }
  int t = threadIdx.x;            // 128 threads
  __shared__ float xs[RPB][128];
  for (int r = 0; r < RPB; r++) {
    int row = r0 + r;
    xs[r][t] = (row < nrows) ? x[(size_t)row*128 + t] : 0.f;
  }
  __syncthreads();
  const int NJ = OUT/128;
  float acc[RPB][NJ] = {};
  for (int k = 0; k < 128; k++) {
    float wv[NJ];
#pragma unroll
    for (int jj = 0; jj < NJ; jj++) wv[jj] = W[(size_t)k*OUT + t + jj*128];
#pragma unroll
    for (int r = 0; r < RPB; r++) {
      float xv = xs[r][k];
#pragma unroll
      for (int jj = 0; jj < NJ; jj++) acc[r][jj] += xv * wv[jj];
    }
  }
  for (int r = 0; r < RPB; r++) {
    int row = r0 + r;
    if (row >= nrows) break;
#pragma unroll
    for (int jj = 0; jj < NJ; jj++)
      o[(size_t)row*OUT + t + jj*128] = acc[r][jj] + b[t + jj*128];
  }
}

// ---- fused relation transform, all 3 edge types, one unified ktv buffer ----
// ktv slot layout: [slot][h][0..31]=k*prel/sqrt(d)*log2e, [h][32..63]=v.  1KB/slot.
// slots: type0 -> [0,Na), type1 -> [Na,2Na), type2 -> [2Na, 2Na+Nb)
__global__ void rel3(const float* __restrict__ o_a, const float* __restrict__ o_b,
                     const float* __restrict__ arelL, const float* __restrict__ mrelL,
                     const float* __restrict__ prelL,
                     float* __restrict__ ktv, int Na, int Nb, int Ga, int Gb) {
  int t = threadIdx.x;            // 128
  int h = t >> 5, e = t & 31;
  int type, blk;
  if ((int)blockIdx.x < Ga)        { type = 0; blk = blockIdx.x; }
  else if ((int)blockIdx.x < 2*Ga) { type = 1; blk = blockIdx.x - Ga; }
  else                             { type = 2; blk = blockIdx.x - 2*Ga; }
  const float* o = (type < 2) ? o_a : o_b;
  int n = (type < 2) ? Na : Nb;
  int G = (type < 2) ? Ga : Gb;
  int slotbase = type * Na;
  const float* ar_ = arelL + type*4096;
  const float* mr_ = mrelL + type*4096;
  float psc = prelL[type*4 + h] * 0.17677669529663688f * 1.4426950408889634f;
  float ar[32], mr[32];
#pragma unroll
  for (int d = 0; d < 32; d++) {
    ar[d] = ar_[(h*32 + d)*32 + e];
    mr[d] = mr_[(h*32 + d)*32 + e];
  }
  __shared__ float ks[128], vs[128];
  int rpb = (n + G - 1)/G;
  int rbeg = blk * rpb;
  int rend = rbeg + rpb; if (rend > n) rend = n;
  for (int row = rbeg; row < rend; row++) {
    __syncthreads();
    ks[t] = o[(size_t)row*384 + t];
    vs[t] = o[(size_t)row*384 + 256 + t];
    __syncthreads();
    float ak = 0.f, av = 0.f;
#pragma unroll
    for (int d = 0; d < 32; d++) {
      ak += ks[h*32 + d] * ar[d];
      av += vs[h*32 + d] * mr[d];
    }
    ktv[(size_t)(slotbase + row)*256 + h*64 + e]      = ak * psc;
    ktv[(size_t)(slotbase + row)*256 + h*64 + 32 + e] = av;
  }
}

// ---------- CSR build (dst-sorted; pure edges, no self loops) ----------
__global__ void hist_init(int* __restrict__ hist, int N) {
  int i = blockIdx.x*blockDim.x + threadIdx.x;
  if (i < N) hist[i] = 0;
}
__global__ void hist_count_all(const int* __restrict__ aa, const int* __restrict__ ab,
                               const int* __restrict__ ba,
                               int Eaa, int Eab, int Eba, int Na, int* __restrict__ hist) {
  int i = blockIdx.x*blockDim.x + threadIdx.x;
  int tot = Eaa + Eab + Eba;
  if (i >= tot) return;
  int dst;
  if (i < Eaa)            dst = aa[Eaa + i];
  else if (i < Eaa + Eab) dst = ab[Eab + (i - Eaa)] + Na;
  else                    dst = ba[Eba + (i - Eaa - Eab)];
  atomicAdd(hist + dst, 1);
}
__global__ void scan_excl(const int* __restrict__ hist, int* __restrict__ roff, int N) {
  __shared__ int part[1024];
  int t = threadIdx.x;
  int chunk = (N + 1023) / 1024;
  int b = t*chunk, e = b + chunk; if (e > N) e = N; if (b > N) b = N;
  int sum = 0;
  for (int i = b; i < e; i++) sum += hist[i];
  part[t] = sum;
  __syncthreads();
  for (int o = 1; o < 1024; o <<= 1) {
    int v = (t >= o) ? part[t - o] : 0;
    __syncthreads();
    part[t] += v;
    __syncthreads();
  }
  int run = (t == 0) ? 0 : part[t - 1];
  for (int i = b; i < e; i++) { roff[i] = run; run += hist[i]; }
  if (t == 1023) roff[N] = run;
}
// epack stores the unified ktv slot directly.
__global__ void fill_all(const int* __restrict__ aa, const int* __restrict__ ab,
                         const int* __restrict__ ba,
                         int Eaa, int Eab, int Eba, int Na,
                         int* __restrict__ cursor, int* __restrict__ epack) {
  int i = blockIdx.x*blockDim.x + threadIdx.x;
  int tot = Eaa + Eab + Eba;
  if (i >= tot) return;
  int dst, slot;
  if (i < Eaa)            { dst = aa[Eaa + i];                slot = aa[i]; }
  else if (i < Eaa + Eab) { int j = i - Eaa;       dst = ab[Eab + j] + Na; slot = ab[j] + Na; }
  else                    { int j = i - Eaa - Eab; dst = ba[Eba + j];      slot = ba[j] + 2*Na; }
  int pos = atomicAdd(cursor + dst, 1);
  epack[pos] = slot;
}

// ---------- fused HGT attention: score + online softmax (base-2) + aggregate ----------
// one wave per dst node; quarter-wave (16 lanes) per head, 2 dims per lane.
// software-pipelined: edge i+1's k/v loads issue before edge i's shuffle chain.
__global__ void seg_attn(const float* __restrict__ o_a, const float* __restrict__ o_b,
                         const float* __restrict__ ktv,
                         const int* __restrict__ roff, const int* __restrict__ epack,
                         float* __restrict__ agg, int Na, int N) {
  int wid = (blockIdx.x*blockDim.x + threadIdx.x) >> 6;
  int lane = threadIdx.x & 63;
  if (wid >= N) return;
  int h = lane >> 4;            // head
  int d0 = (lane & 15) * 2;     // dims d0, d0+1 of head h
  const float* qrow = (wid < Na) ? (o_a + (size_t)wid*384 + 128)
                                 : (o_b + (size_t)(wid - Na)*384 + 128);
  float2 q = *(const float2*)(qrow + h*32 + d0);
  int beg = roff[wid], end = roff[wid + 1];
  float m = -INFINITY, s = 0.f, a0 = 0.f, a1 = 0.f;
  if (beg < end) {
    const float* kp = ktv + (size_t)epack[beg]*256 + h*64 + d0;
    float2 kv = *(const float2*)kp;
    float2 vv = *(const float2*)(kp + 32);
    for (int i = beg; i < end; i++) {
      float2 ck = kv, cv = vv;
      if (i + 1 < end) {   // prefetch next edge
        const float* kpn = ktv + (size_t)epack[i+1]*256 + h*64 + d0;
        kv = *(const float2*)kpn;
        vv = *(const float2*)(kpn + 32);
      }
      float sc = q.x*ck.x + q.y*ck.y;
      sc += __shfl_xor(sc, 1, 64);
      sc += __shfl_xor(sc, 2, 64);
      sc += __shfl_xor(sc, 4, 64);
      sc += __shfl_xor(sc, 8, 64);   // per-head score, base-2 scaled
      float nm = fmaxf(m, sc);
      float scale = exp2f(m - nm);   // first edge: exp2(-inf)=0
      float e = exp2f(sc - nm);
      s  = s*scale  + e;
      a0 = a0*scale + e*cv.x;
      a1 = a1*scale + e*cv.y;
      m = nm;
    }
  }
  float inv = 1.f / (s + 1e-16f);
  float2 o2; o2.x = a0*inv; o2.y = a1*inv;
  *(float2*)(agg + (size_t)wid*128 + h*32 + d0) = o2;
}

// ---- fused finish for both types: gelu(agg) @ Wout + bout, gated skip, opt gelu ----
template<int RPB>
__global__ void finish2(const float* __restrict__ agg,
                        const float* __restrict__ xa, const float* __restrict__ xb,
                        float* __restrict__ ha, float* __restrict__ hb,
                        const float* __restrict__ WoL, const float* __restrict__ boL,
                        const float* __restrict__ skipL, int do_gelu, int Na, int Nb) {
  int nba = (Na + RPB - 1)/RPB;
  const float *xsrc, *Wo, *bo; float* h; float sgraw; int nrows, r0, aggoff;
  if ((int)blockIdx.x < nba) { xsrc=xa; h=ha; Wo=WoL; bo=boL; sgraw=skipL[0]; nrows=Na; r0=blockIdx.x*RPB; aggoff=0; }
  else { xsrc=xb; h=hb; Wo=WoL+16384; bo=boL+128; sgraw=skipL[1]; nrows=Nb; r0=(blockIdx.x-nba)*RPB; aggoff=Na; }
  int t = threadIdx.x;            // 128
  __shared__ float gs[RPB][128];
  for (int r = 0; r < RPB; r++) {
    int row = r0 + r;
    float a = (row < nrows) ? agg[(size_t)(row + aggoff)*128 + t] : 0.f;
    gs[r][t] = gelu_f(a);
  }
  __syncthreads();
  float acc[RPB] = {};
  for (int k = 0; k < 128; k++) {
    float wv = Wo[(size_t)k*128 + t];
#pragma unroll
    for (int r = 0; r < RPB; r++) acc[r] += gs[r][k]*wv;
  }
  float sg = 1.f/(1.f + expf(-sgraw));
  for (int r = 0; r < RPB; r++) {
    int row = r0 + r;
    if (row >= nrows) break;
    float g = acc[r] + bo[t];
    float v = sg*g + (1.f - sg)*xsrc[(size_t)row*128 + t];
    h[(size_t)row*128 + t] = do_gelu ? gelu_f(v) : v;
  }
}

// LayerNorm over 128 then gelu, in place, both types. One wave per row.
__global__ void ln_gelu2(float* __restrict__ h, const float* __restrict__ g,
                         const float* __restrict__ b, int Na, int N) {
  int idx = blockIdx.x*blockDim.x + threadIdx.x;
  int row = idx >> 6, lane = idx & 63;
  if (row >= N) return;
  int po = (row < Na) ? 0 : 128;
  float x0 = h[(size_t)row*128 + lane];
  float x1 = h[(size_t)row*128 + 64 + lane];
  float sum = x0 + x1;
#pragma unroll
  for (int o = 32; o; o >>= 1) sum += __shfl_xor(sum, o, 64);
  float mu = sum * (1.f/128.f);
  float d0 = x0 - mu, d1 = x1 - mu;
  float vs = d0*d0 + d1*d1;
#pragma unroll
  for (int o = 32; o; o >>= 1) vs += __shfl_xor(vs, o, 64);
  float inv = 1.f / sqrtf(vs*(1.f/128.f) + 1e-5f);
  h[(size_t)row*128 + lane]      = gelu_f(d0*inv*g[po + lane] + b[po + lane]);
  h[(size_t)row*128 + 64 + lane] = gelu_f(d1*inv*g[po + 64 + lane] + b[po + 64 + lane]);
}

// x1[n] = dot(h[n,:], Wgat[:,0]) — one wave per row
__global__ void gat_x1(const float* __restrict__ h, const float* __restrict__ Wg,
                       float* __restrict__ x1, int N) {
  int idx = blockIdx.x*blockDim.x + threadIdx.x;
  int row = idx >> 6, lane = idx & 63;
  if (row >= N) return;
  float a = h[(size_t)row*128 + lane]*Wg[lane] + h[(size_t)row*128 + 64 + lane]*Wg[64 + lane];
#pragma unroll
  for (int o = 32; o; o >>= 1) a += __shfl_xor(a, o, 64);
  if (lane == 0) x1[row] = a;
}

// fused GAT scorer via CSR: thread per node, online softmax (self-loop handled inline)
__global__ void gat_all(const float* __restrict__ x1, const int* __restrict__ roff,
                        const int* __restrict__ epack,
                        const float* __restrict__ asrc, const float* __restrict__ adst,
                        int Na, int N, float* __restrict__ score) {
  int n = blockIdx.x*blockDim.x + threadIdx.x;
  if (n >= N) return;
  float xd = x1[n];
  float as_ = asrc[0], ad = adst[0];
  // self loop first: e = leaky(xd*as + xd*ad), weight exp(0)=1 at m=e
  float e0 = xd*as_ + xd*ad;
  e0 = (e0 > 0.f) ? e0 : 0.2f*e0;
  float m = e0, s = 1.f, acc = xd;
  int beg = roff[n], end = roff[n + 1];
  for (int i = beg; i < end; i++) {
    int slot = epack[i];
    int sg = (slot < Na) ? slot : slot - Na;   // global src node index
    float xs = x1[sg];
    float e = xs*as_ + xd*ad;
    e = (e > 0.f) ? e : 0.2f*e;
    float nm = fmaxf(m, e);
    float sc = __expf(m - nm), ee = __expf(e - nm);
    s = s*sc + ee;  acc = acc*sc + ee*xs;  m = nm;
  }
  score[n] = acc / (s + 1e-16f);
}

// ---- parallel top-8 ----
__global__ void topk_stage1(const float* __restrict__ score, const float* __restrict__ bgat,
                            int N, float* __restrict__ cvals, int* __restrict__ cidx) {
  __shared__ float bv[256];
  __shared__ int   bi[256];
  int t = threadIdx.x;
  int chunk = (N + gridDim.x - 1) / gridDim.x;   // <= 256 by construction
  int i = blockIdx.x * chunk + t;
  float bg = bgat[0];
  bool valid = (t < chunk && i < N);
  float myv = valid ? score[i] + bg : -INFINITY;
  int   myi = valid ? i : 0x7FFFFFFF;
  for (int k = 0; k < 8; k++) {
    bv[t] = myv; bi[t] = myi;
    __syncthreads();
    for (int o = 128; o; o >>= 1) {
      if (t < o) {
        if (bv[t+o] > bv[t] || (bv[t+o] == bv[t] && bi[t+o] < bi[t])) { bv[t]=bv[t+o]; bi[t]=bi[t+o]; }
      }
      __syncthreads();
    }
    if (t == 0) { cvals[blockIdx.x*8 + k] = bv[0]; cidx[blockIdx.x*8 + k] = bi[0]; }
    if (myi == bi[0]) myv = -INFINITY;   // pop winner
    __syncthreads();
  }
}

__global__ void topk_stage2(const float* __restrict__ cvals, const int* __restrict__ cidx,
                            int C, float* __restrict__ vals, int* __restrict__ perm) {
  __shared__ float bv[256];
  __shared__ int   bi[256];
  __shared__ int   seli[8];
  int t = threadIdx.x;
  for (int k = 0; k < 8; k++) {
    float best = -INFINITY; int besti = 0x7FFFFFFF;
    for (int i = t; i < C; i += 256) {
      int id = cidx[i];
      bool taken = false;
      for (int j = 0; j < k; j++) if (seli[j] == id) taken = true;
      if (taken) continue;
      float v = cvals[i];
      if (v > best || (v == best && id < besti)) { best = v; besti = id; }
    }
    bv[t] = best; bi[t] = besti;
    __syncthreads();
    for (int o = 128; o; o >>= 1) {
      if (t < o) {
        if (bv[t+o] > bv[t] || (bv[t+o] == bv[t] && bi[t+o] < bi[t])) { bv[t]=bv[t+o]; bi[t]=bi[t+o]; }
      }
      __syncthreads();
    }
    if (t == 0) { seli[k] = bi[0]; vals[k] = bv[0]; perm[k] = bi[0]; }
    __syncthreads();
  }
}

__global__ void mlp_final(const float* __restrict__ h, const float* __restrict__ vals,
                          const int* __restrict__ perm,
                          const float* __restrict__ W1, const float* __restrict__ b1,
                          const float* __restrict__ W2, const float* __restrict__ b2,
                          const float* __restrict__ W3, const float* __restrict__ b3,
                          float* __restrict__ out) {
  __shared__ float hp[1024], v1[128], v2[64];
  int t = threadIdx.x;  // 256
  for (int i = t; i < 1024; i += 256) {
    int r = i >> 7, d = i & 127;
    hp[i] = h[(size_t)perm[r]*128 + d] * tanhf(vals[r]);
  }
  __syncthreads();
  if (t < 128) {
    float a = 0.f;
    for (int k = 0; k < 1024; k++) a += hp[k]*W1[(size_t)k*128 + t];
    v1[t] = gelu_f(a + b1[t]);
  }
  __syncthreads();
  if (t < 64) {
    float a = 0.f;
    for (int k = 0; k < 128; k++) a += v1[k]*W2[(size_t)k*64 + t];
    v2[t] = gelu_f(a + b2[t]);
  }
  __syncthreads();
  if (t < 16) {
    float a = 0.f;
    for (int k = 0; k < 64; k++) a += v2[k]*W3[(size_t)k*16 + t];
    float r = gelu_f(a + b3[t]);
    if (isnan(r)) r = 0.f;
    else if (isinf(r)) r = (r > 0.f) ? 3.4028234663852886e38f : -3.4028234663852886e38f;
    out[t] = r;
  }
}

extern "C" void kernel_launch(void* const* d_in, const int* in_sizes, int n_in,
                              void* d_out, int out_size, void* d_ws, size_t ws_size,
                              hipStream_t stream) {
  const float* x_a  = (const float*)d_in[0];
  const float* x_b  = (const float*)d_in[1];
  const int* ei_aa  = (const int*)d_in[2];
  const int* ei_ab  = (const int*)d_in[3];
  const int* ei_ba  = (const int*)d_in[4];
  const float* Wkqv = (const float*)d_in[5];
  const float* bkqv = (const float*)d_in[6];
  const float* Wout = (const float*)d_in[7];
  const float* bout = (const float*)d_in[8];
  const float* skip = (const float*)d_in[9];
  const float* arel = (const float*)d_in[10];
  const float* mrel = (const float*)d_in[11];
  const float* prel = (const float*)d_in[12];
  const float* ln_g = (const float*)d_in[13];
  const float* ln_b = (const float*)d_in[14];
  const float* Wgat = (const float*)d_in[15];
  const float* att_src = (const float*)d_in[16];
  const float* att_dst = (const float*)d_in[17];
  const float* bgat = (const float*)d_in[18];
  const float* W1 = (const float*)d_in[19];
  const float* b1 = (const float*)d_in[20];
  const float* W2 = (const float*)d_in[21];
  const float* b2 = (const float*)d_in[22];
  const float* W3 = (const float*)d_in[23];
  const float* b3 = (const float*)d_in[24];

  int Na = in_sizes[0]/128, Nb = in_sizes[1]/128, N = Na + Nb;
  int Eaa = in_sizes[2]/2, Eab = in_sizes[3]/2, Eba = in_sizes[4]/2;
  int Etot = Eaa + Eab + Eba;

  // workspace layout
  float* w = (float*)d_ws;
  size_t off = 0;
  auto alloc = [&](size_t n) { float* p = w + off; off += n; return p; };
  float* hbuf = alloc((size_t)N*128);
  float* o_a  = alloc((size_t)Na*384);
  float* o_b  = alloc((size_t)Nb*384);
  float* ktvA = alloc((size_t)(2*Na + Nb)*256);   // unified, slot-indexed
  float* agg   = alloc((size_t)N*128);
  float* x1buf = alloc((size_t)N);
  float* score = alloc((size_t)N);
  float* valsb = alloc(8);
  int*   permb = (int*)alloc(8);
  float* cvals = alloc(2048);
  int*   cidx  = (int*)alloc(2048);
  int*   hist  = (int*)alloc((size_t)N);
  int*   roff  = (int*)alloc((size_t)N + 1);
  int*   cursor= (int*)alloc((size_t)N);
  int*   epack = (int*)alloc((size_t)Etot);

  float* h_a = hbuf;
  float* h_b = hbuf + (size_t)Na*128;

  // ---- build dst-sorted CSR once (pure edges; self-loops handled analytically) ----
  hist_init<<<dim3((N+255)/256),dim3(256),0,stream>>>(hist, N);
  hist_count_all<<<dim3((Etot+255)/256),dim3(256),0,stream>>>(ei_aa, ei_ab, ei_ba, Eaa, Eab, Eba, Na, hist);
  scan_excl<<<dim3(1),dim3(1024),0,stream>>>(hist, roff, N);
  hipMemcpyAsync(cursor, roff, (size_t)N*sizeof(int), hipMemcpyDeviceToDevice, stream);
  fill_all<<<dim3((Etot+255)/256),dim3(256),0,stream>>>(ei_aa, ei_ab, ei_ba, Eaa, Eab, Eba, Na, cursor, epack);

  const int RPB = 8;
  int nba = (Na + RPB - 1)/RPB, nbb = (Nb + RPB - 1)/RPB;
  const int Ga = 1024, Gb = 1024;

  for (int L = 0; L < 3; L++) {
    const float* xa_in = (L == 0) ? x_a : h_a;
    const float* xb_in = (L == 0) ? x_b : h_b;
    const float* WL = Wkqv + (size_t)L*2*49152;
    const float* bL = bkqv + (size_t)L*2*384;
    rowmm2<RPB><<<dim3(nba + nbb),dim3(128),0,stream>>>(xa_in, xb_in, WL, WL + 49152,
                                                        bL, bL + 384, o_a, o_b, Na, Nb);
    rel3<<<dim3(2*Ga + Gb),dim3(128),0,stream>>>(o_a, o_b,
                                                 arel + (size_t)L*3*4096, mrel + (size_t)L*3*4096,
                                                 prel + (size_t)L*3*4, ktvA, Na, Nb, Ga, Gb);
    seg_attn<<<dim3((N+3)/4),dim3(256),0,stream>>>(o_a, o_b, ktvA, roff, epack, agg, Na, N);
    int do_gelu = (L == 0) ? 0 : 1;
    finish2<RPB><<<dim3(nba + nbb),dim3(128),0,stream>>>(agg, xa_in, xb_in, h_a, h_b,
                                                         Wout + (size_t)L*2*16384,
                                                         bout + (size_t)L*2*128,
                                                         skip + L*2, do_gelu, Na, Nb);
    if (L == 0) {
      ln_gelu2<<<dim3((N+3)/4),dim3(256),0,stream>>>(hbuf, ln_g, ln_b, Na, N);
    }
  }

  // ---- GAT scorer + SAGPool top-k + MLP ----
  gat_x1<<<dim3((N+3)/4),dim3(256),0,stream>>>(hbuf, Wgat, x1buf, N);
  gat_all<<<dim3((N+255)/256),dim3(256),0,stream>>>(x1buf, roff, epack, att_src, att_dst, Na, N, score);
  int tk_blocks = (N + 255)/256;
  topk_stage1<<<dim3(tk_blocks),dim3(256),0,stream>>>(score, bgat, N, cvals, cidx);
  topk_stage2<<<dim3(1),dim3(256),0,stream>>>(cvals, cidx, tk_blocks*8, valsb, permb);
  mlp_final<<<dim3(1),dim3(256),0,stream>>>(hbuf, valsb, permb, W1, b1, W2, b2, W3, b3, (float*)d_out);
}